// Round 5
// baseline (482.509 us; speedup 1.0000x reference)
//
#include <hip/hip_runtime.h>
#include <cstdint>
#include <math.h>

// MoE top-2 of 16 experts. N=131072, D=512, H=128, E=16, O=512.  All-fp16 path:
//   memset CTRL -> kconv (We->Wt f16 [O][D], Wg1->W1 f16 [H][D], Wg2->frag-order f16)
//   -> kgate (1-MFMA fp16 GEMM1 + MFMA GEMM2 + fp64 softmax/top2 + x-f16 store +
//             pair histogram; margin 2e-3 flags ambiguous)
//   -> krefine (fp64 exact gating for flagged tokens; patches pair counts)
//   -> kscan (one-wave shuffle prefix scan + tile list) -> kscatter
//   -> kexpert2 (pair-bucket f16 GEMM, 256 tok x 256 cols, 8-phase counted-vmcnt,
//      both operands via global_load_lds w/ pre-swizzled per-lane source;
//      gate-A folded into accumulator; single store, no atomics)

#define NTOK 131072
#define DDIM 512
#define NT 16          // K-tiles in kexpert2: 8 per expert x 2 experts

typedef _Float16 f16;
typedef f16   f16x8 __attribute__((ext_vector_type(8)));
typedef float f32x4 __attribute__((ext_vector_type(4)));

__device__ __forceinline__ void load_lds16(const void* g, void* l){
  __builtin_amdgcn_global_load_lds(
      (const __attribute__((address_space(1))) void*)(uintptr_t)g,
      (__attribute__((address_space(3))) void*)(uintptr_t)l, 16, 0, 0);
}

__device__ __forceinline__ f32x4 MFMAH(f16x8 a, f16x8 b, f32x4 c){
  return __builtin_amdgcn_mfma_f32_16x16x32_f16(a, b, c, 0, 0, 0);
}

// ---- swizzled LDS helpers -----------------------------------------------------
// 64-col f16 tile (pitch 128B): logical (row r, 16B chunk q) at r*128+((q^(r&7))<<4)
__device__ __forceinline__ f16x8 readF64h(const char* buf, int r, int q){
  return *(const f16x8*)(buf + r*128 + ((q ^ (r & 7)) << 4));
}
// 32-col f16 tile (pitch 64B)
__device__ __forceinline__ f16x8 readF32h(const char* buf, int r, int q){
  return *(const f16x8*)(buf + r*64 + ((q ^ (r & 3)) << 4));
}
__device__ __forceinline__ f16x8 pack8f(const float* fv){
  f16x8 v;
  #pragma unroll
  for (int j=0;j<8;++j) v[j] = (f16)fv[j];   // RNE v_cvt_f16_f32
  return v;
}

// stage [128 rows][32 cols] f16 (8KB) via global_load_lds; global pitch 1024B.
__device__ __forceinline__ void stageB32(const void* grow, char* lds, int tid){
  const char* gb = (const char*)grow;
  #pragma unroll
  for (int i = 0; i < 2; ++i){
    int lin = i*4096 + tid*16;
    int r = lin >> 6;
    int g = (lin >> 4) & 3;
    load_lds16(gb + r*1024 + ((g ^ (r & 3)) << 4), lds + i*4096 + ((tid >> 6) << 10));
  }
}

// ---- kconv: We [E][D][O] f32 -> Wt f16 [E][O][D]; Wg1 [D][H] f32 -> W1 f16 [H][D];
//             Wg2 [H][E] f32 -> Wg2f fragment-order f16 [ks][lane][8]
__global__ void kconv(const float* __restrict__ We, const float* __restrict__ Wg1,
                      const float* __restrict__ Wg2,
                      f16* __restrict__ Wt, f16* __restrict__ W1, char* __restrict__ Wg2f){
  __shared__ float sh[64*65];
  int bx = blockIdx.x, tid = threadIdx.x;
  if (bx < 1024){
    int e = bx >> 6, dt = (bx >> 3) & 7, ot = bx & 7;
    const float* src = We + (size_t)e*262144 + (size_t)dt*64*512 + ot*64;
    #pragma unroll
    for (int it=0; it<16; ++it){ int idx = it*256+tid; int dl = idx>>6, ol = idx&63;
      sh[dl*65+ol] = src[dl*512+ol]; }
    __syncthreads();
    f16* dst = Wt + (size_t)e*262144 + (size_t)ot*64*512 + dt*64;
    #pragma unroll
    for (int it=0; it<16; ++it){ int idx = it*256+tid; int ol = idx>>6, dl = idx&63;
      dst[(size_t)ol*512+dl] = (f16)sh[dl*65+ol]; }
  } else if (bx < 1040){
    int q = bx - 1024;
    int dt = q >> 1, ht = q & 1;
    const float* src = Wg1 + (size_t)dt*64*128 + ht*64;
    #pragma unroll
    for (int it=0; it<16; ++it){ int idx = it*256+tid; int dl = idx>>6, ol = idx&63;
      sh[dl*65+ol] = src[dl*128+ol]; }
    __syncthreads();
    #pragma unroll
    for (int it=0; it<16; ++it){ int idx = it*256+tid; int ol = idx>>6, dl = idx&63;
      W1[(size_t)(ht*64+ol)*512 + dt*64+dl] = (f16)sh[dl*65+ol]; }
  } else {
    // Wg2 -> MFMA B-fragment order: frag[ks][lane][j] = Wg2[ks*32+(lane>>4)*8+j][lane&15]
    int ks = tid >> 6, l = tid & 63;
    int col = l & 15, kb = ks*32 + ((l >> 4) << 3);
    f16x8 v;
    #pragma unroll
    for (int j=0;j<8;++j) v[j] = (f16)Wg2[(kb+j)*16 + col];
    *(f16x8*)(Wg2f + (ks*64+l)*16) = v;
  }
}

// ---- kgate: fp16 gating + x-f16 producer + pair histogram. 64 tok/block, 256 thr.
__global__ __launch_bounds__(256) void kgate(
    const float* __restrict__ x, const f16* __restrict__ W1, const char* __restrict__ Wg2f,
    const float* __restrict__ bg1, const float* __restrict__ bg2,
    f16* __restrict__ xbf,
    int2* __restrict__ gate_e, float2* __restrict__ gate_g,
    int* __restrict__ refine_cnt, int* __restrict__ refine_list, int* __restrict__ counts)
{
  __shared__ __align__(16) char sm[38912];
  const int BOFF = 8192;     // B dbuf 2x8KB at [8192,24576); A dbuf 2x4KB at [0,8192)
  int tid = threadIdx.x, bid = blockIdx.x;
  int lane = tid & 63, w = tid >> 6, wm = w >> 1, wn = w & 1;
  int l15 = lane & 15, l4 = lane >> 4;
  int t0 = bid * 64;
  int ar = tid >> 2, acq = tid & 3;
  const float* xrow = x + (size_t)(t0 + ar) * DDIM;
  char* xbfb = (char*)xbf;
  f32x4 acc[2][4];
  #pragma unroll
  for (int n=0;n<4;++n){
    float bb = bg1[wn*64 + n*16 + l15];
    f32x4 z = {bb, bb, bb, bb};
    acc[0][n] = z; acc[1][n] = z;
  }
  // prologue ks=0
  stageB32(W1, sm + BOFF, tid);
  {
    float fv[8];
    *(float4*)&fv[0] = *(const float4*)(xrow + acq*8);
    *(float4*)&fv[4] = *(const float4*)(xrow + acq*8 + 4);
    f16x8 v8 = pack8f(fv);
    if (xbf) *(f16x8*)(xbfb + (size_t)(t0+ar)*1024 + acq*16) = v8;
    *(f16x8*)(sm + ar*64 + ((acq ^ (ar & 3)) << 4)) = v8;
  }
  for (int ks = 0; ks < 16; ++ks){
    int b = ks & 1;
    asm volatile("s_waitcnt vmcnt(0)" ::: "memory");
    __syncthreads();
    f16x8 v8;
    if (ks < 15){
      int k2 = ks + 1, b2 = k2 & 1;
      stageB32((const char*)W1 + k2*64, sm + BOFF + b2*8192, tid);
      float fv[8];
      *(float4*)&fv[0] = *(const float4*)(xrow + k2*32 + acq*8);
      *(float4*)&fv[4] = *(const float4*)(xrow + k2*32 + acq*8 + 4);
      v8 = pack8f(fv);
      if (xbf) *(f16x8*)(xbfb + (size_t)(t0+ar)*1024 + k2*64 + acq*16) = v8;
    }
    const char* Ab = sm + b*4096;
    const char* Bb = sm + BOFF + b*8192;
    f16x8 ah[2], bh[4];
    #pragma unroll
    for (int m=0;m<2;++m) ah[m] = readF32h(Ab, wm*32 + m*16 + l15, l4);
    #pragma unroll
    for (int n=0;n<4;++n) bh[n] = readF32h(Bb, wn*64 + n*16 + l15, l4);
    #pragma unroll
    for (int m=0;m<2;++m)
      #pragma unroll
      for (int n=0;n<4;++n) acc[m][n] = MFMAH(ah[m], bh[n], acc[m][n]);
    if (ks < 15){
      int b2 = (ks + 1) & 1;
      *(f16x8*)(sm + b2*4096 + ar*64 + ((acq ^ (ar & 3)) << 4)) = v8;
    }
  }
  __syncthreads();
  // prefetch Wg2 B-fragments (lane-indexed, same for all waves)
  uint4 wgf[4];
  #pragma unroll
  for (int ksq=0; ksq<4; ++ksq) wgf[ksq] = *(const uint4*)(Wg2f + (ksq*64+lane)*16);
  // GELU (exact erf) -> h f32 [64][132] at sm+0 (A/B bufs dead)
  float* hl = (float*)sm;
  #pragma unroll
  for (int m=0;m<2;++m)
    #pragma unroll
    for (int n=0;n<4;++n)
      #pragma unroll
      for (int j=0;j<4;++j){
        int row = wm*32 + m*16 + (l4 << 2) + j;
        int col = wn*64 + n*16 + l15;
        float uv = acc[m][n][j];
        hl[row*132 + col] = 0.5f * uv * (1.0f + erff(uv * 0.70710678118654752f));
      }
  __syncthreads();
  // GEMM2 via MFMA: logits[64][16]; wave w -> token rows w*16..+15
  {
    float bb2 = bg2[l15];
    f32x4 acc2 = {bb2, bb2, bb2, bb2};
    #pragma unroll
    for (int ksq=0; ksq<4; ++ksq){
      const float* hp = (const float*)sm + (w*16 + l15)*132 + ksq*32 + l4*8;
      f16x8 afr;
      #pragma unroll
      for (int j=0;j<8;++j) afr[j] = (f16)hp[j];
      acc2 = MFMAH(afr, *(const f16x8*)&wgf[ksq], acc2);
    }
    float* ll = (float*)(sm + 33792);
    #pragma unroll
    for (int j=0;j<4;++j) ll[(w*16 + l4*4 + j)*16 + l15] = acc2[j];
  }
  int* hist = (int*)(sm + 37888);
  hist[tid] = 0;
  __syncthreads();
  if (tid < 64){
    int t = t0 + tid;
    const float* l = (const float*)(sm + 33792) + tid*16;
    float b1 = -1e30f, b2 = -1e30f, b3 = -1e30f; int e1 = 0, e2 = 0;
    #pragma unroll
    for (int e = 0; e < 16; ++e){
      float v = l[e];
      if (v > b1){ b3 = b2; b2 = b1; e2 = e1; b1 = v; e1 = e; }
      else if (v > b2){ b3 = b2; b2 = v; e2 = e; }
      else if (v > b3){ b3 = v; }
    }
    double s = 0.0;
    #pragma unroll
    for (int e = 0; e < 16; ++e) s += exp((double)l[e] - (double)b1);
    double inv = 1.0 / s;
    gate_e[t] = make_int2(e1, e2);
    gate_g[t] = make_float2((float)(inv + 1e-4), (float)(exp((double)b2 - (double)b1) * inv + 1e-4));
    if (b2 - b3 < 2e-3f){            // fp16-path margin: flag ambiguous top2/top3
      int pos = atomicAdd(refine_cnt, 1);
      refine_list[pos] = t;
    }
    int pa = min(e1, e2), pb = max(e1, e2);
    atomicAdd(&hist[pa*16 + pb], 1);
  }
  __syncthreads();
  if (hist[tid]) atomicAdd(&counts[tid], hist[tid]);
}

// ---- krefine: exact fp64 gating for flagged tokens; patches pair counts.
__global__ __launch_bounds__(128) void krefine(
    const float* __restrict__ x, const float* __restrict__ Wg1, const float* __restrict__ bg1,
    const float* __restrict__ Wg2, const float* __restrict__ bg2,
    const int* __restrict__ refine_cnt, const int* __restrict__ refine_list,
    int2* __restrict__ gate_e, float2* __restrict__ gate_g, int* __restrict__ counts)
{
  __shared__ float  xs[512];
  __shared__ double hd[128];
  __shared__ double ld[16];
  int tid = threadIdx.x;
  int rc = *refine_cnt;
  for (int i = blockIdx.x; i < rc; i += gridDim.x){
    __syncthreads();
    int t = refine_list[i];
    *(float4*)(xs + tid*4) = *(const float4*)(x + (size_t)t*DDIM + tid*4);
    __syncthreads();
    double a = (double)bg1[tid];
    for (int d = 0; d < 512; ++d) a += (double)xs[d] * (double)Wg1[d*128 + tid];
    hd[tid] = 0.5 * a * (1.0 + erf(a * 0.70710678118654752440));
    __syncthreads();
    if (tid < 16){
      double s = (double)bg2[tid];
      for (int k = 0; k < 128; ++k) s += hd[k] * (double)Wg2[k*16 + tid];
      ld[tid] = s;
    }
    __syncthreads();
    if (tid == 0){
      int2 olde = gate_e[t];
      double b1 = -1e300, b2 = -1e300; int e1 = 0, e2 = 0;
      for (int e = 0; e < 16; ++e){
        double v = ld[e];
        if (v > b1){ b2 = b1; e2 = e1; b1 = v; e1 = e; }
        else if (v > b2){ b2 = v; e2 = e; }
      }
      double s = 0.0;
      for (int e = 0; e < 16; ++e) s += exp(ld[e] - b1);
      double inv = 1.0 / s;
      int oldp = min(olde.x, olde.y)*16 + max(olde.x, olde.y);
      int newp = min(e1, e2)*16 + max(e1, e2);
      if (oldp != newp){ atomicSub(&counts[oldp], 1); atomicAdd(&counts[newp], 1); }
      gate_e[t] = make_int2(e1, e2);
      gate_g[t] = make_float2((float)(inv + 1e-4), (float)(exp(b2 - b1) * inv + 1e-4));
    }
  }
}

// ---- kscan: one wave. prefix over 256 pair counts + tile list (ts-row tiles).
__global__ void kscan(const int* __restrict__ counts, int* __restrict__ bases,
                      int* __restrict__ tile_pair, int* __restrict__ tile_row0, int* __restrict__ ntiles,
                      int ts){
  int l = threadIdx.x;
  int4 c = *(const int4*)(counts + l*4);
  int s = c.x + c.y + c.z + c.w;
  int ps = s;
  #pragma unroll
  for (int d = 1; d < 64; d <<= 1){ int v = __shfl_up(ps, d); if (l >= d) ps += v; }
  int ex = ps - s;
  bases[4*l+0] = ex;
  bases[4*l+1] = ex + c.x;
  bases[4*l+2] = ex + c.x + c.y;
  bases[4*l+3] = ex + c.x + c.y + c.z;
  if (l == 63) bases[256] = ex + s;
  int t0 = (c.x + ts-1) / ts, t1 = (c.y + ts-1) / ts, t2 = (c.z + ts-1) / ts, t3 = (c.w + ts-1) / ts;
  int tsum = t0 + t1 + t2 + t3;
  int pt = tsum;
  #pragma unroll
  for (int d = 1; d < 64; d <<= 1){ int v = __shfl_up(pt, d); if (l >= d) pt += v; }
  int ext = pt - tsum;
  if (l == 63) *ntiles = ext + tsum;
  int tb = ext;
  int cc[4] = {c.x, c.y, c.z, c.w};
  #pragma unroll
  for (int j = 0; j < 4; ++j){
    int pp = 4*l + j;
    for (int r = 0; r < cc[j]; r += ts){ tile_pair[tb] = pp; tile_row0[tb] = r; ++tb; }
  }
}

__global__ void kscatter(const int2* __restrict__ gate_e, const float2* __restrict__ gate_g,
                         const int* __restrict__ bases, int* __restrict__ cursors,
                         int* __restrict__ pair_tok, float2* __restrict__ pair_g){
  __shared__ int h[256];
  __shared__ int gb[256];
  int tid = threadIdx.x;
  h[tid] = 0; __syncthreads();
  int t = blockIdx.x*256 + tid;
  int2 ee = gate_e[t]; float2 gg = gate_g[t];
  int a, b; float ga, gbv;
  if (ee.x < ee.y){ a = ee.x; b = ee.y; ga = gg.x; gbv = gg.y; }
  else            { a = ee.y; b = ee.x; ga = gg.y; gbv = gg.x; }
  int p = a*16 + b;
  int off = atomicAdd(&h[p], 1);
  __syncthreads();
  if (h[tid]) gb[tid] = bases[tid] + atomicAdd(&cursors[tid], h[tid]);
  __syncthreads();
  int slot = gb[p] + off;
  pair_tok[slot] = t;
  pair_g[slot] = make_float2(ga, gbv);
}

// ======== kexpert2: 256x256 pair-bucket GEMM, 8-phase counted-vmcnt schedule ====
#define SB0 __builtin_amdgcn_sched_barrier(0)
#define PH_MID do{ __builtin_amdgcn_s_barrier(); \
                   asm volatile("s_waitcnt lgkmcnt(0)"); SB0; }while(0)
#define PH_END do{ SB0; __builtin_amdgcn_s_barrier(); }while(0)

#define RDA(hp, mb) do{ \
  _Pragma("unroll") for (int m_=0;m_<4;++m_){ \
    int r_ = ((mb)+m_)*16 + l15; \
    af[m_][0] = readF64h(hp, r_, l4); \
    af[m_][1] = readF64h(hp, r_, 4+l4); }}while(0)
#define RDB(hp, bv, nb) do{ \
  _Pragma("unroll") for (int n_=0;n_<2;++n_){ \
    int r_ = bln + ((nb)+n_)*16 + l15; \
    bv[n_][0] = readF64h(hp, r_, l4); \
    bv[n_][1] = readF64h(hp, r_, 4+l4); }}while(0)
#define MMAC(bv, mb, nb) do{ \
  __builtin_amdgcn_s_setprio(1); \
  _Pragma("unroll") for (int m_=0;m_<4;++m_){ \
    _Pragma("unroll") for (int n_=0;n_<2;++n_){ \
      acc[(mb)+m_][(nb)+n_] = MFMAH(af[m_][0], bv[n_][0], acc[(mb)+m_][(nb)+n_]); \
      acc[(mb)+m_][(nb)+n_] = MFMAH(af[m_][1], bv[n_][1], acc[(mb)+m_][(nb)+n_]); }} \
  __builtin_amdgcn_s_setprio(0); \
}while(0)

__global__ __launch_bounds__(512, 2) void kexpert2(
    const f16* __restrict__ xbf, const f16* __restrict__ Wt, const float* __restrict__ be,
    float* __restrict__ out,
    const int* __restrict__ counts, const int* __restrict__ bases,
    const int* __restrict__ tile_pair, const int* __restrict__ tile_row0, const int* __restrict__ ntiles,
    const int* __restrict__ pair_tok, const float2* __restrict__ pair_g)
{
  __shared__ __align__(16) char sm[134144];
  const int BBASE = 65536, LTOK = 131072, LG = 132096;
  int bid = blockIdx.x;
  int tile = ((bid >> 4) << 3) | (bid & 7);   // col-block pair shares XCD
  int nt = (bid >> 3) & 1;
  if (tile >= *ntiles) return;
  int p = tile_pair[tile], row0 = tile_row0[tile];
  int base = bases[p], cnt = counts[p];
  int eA = p >> 4, eB = p & 15;
  int tid = threadIdx.x, lane = tid & 63, w = tid >> 6;
  int wm = w >> 2, wn = w & 3;
  int l15 = lane & 15, l4 = lane >> 4;
  int bln = (wn & 1) * 64;
  if (tid < 256){
    int rr = row0 + tid; bool v = rr < cnt;
    ((int*)(sm + LTOK))[tid] = v ? pair_tok[base + rr] : -1;
    ((float2*)(sm + LG))[tid] = v ? pair_g[base + rr] : make_float2(0.f, 1.f);
  }
  __syncthreads();

  int rr0 = tid >> 3;
  int sw = ((tid & 7) ^ (rr0 & 7)) << 4;
  const char* xb = (const char*)xbf;
  const char* srcA[2][2];
  #pragma unroll
  for (int h = 0; h < 2; ++h)
    #pragma unroll
    for (int i = 0; i < 2; ++i){
      int tk = ((const int*)(sm + LTOK))[h*128 + i*64 + rr0];
      if (tk < 0) tk = 0;
      srcA[h][i] = xb + (size_t)tk*1024 + sw;
    }
  const char* srcB0 = (const char*)Wt + (size_t)eA*524288 + (size_t)(nt*256 + rr0)*1024 + sw;
  long long edelt = ((long long)eB - eA) * 524288;
  char* dA = sm + w*1024;
  char* dB = sm + BBASE + w*1024;

  auto stA = [&](int t, int h){
    if (t >= NT) return;
    int ks = t & 7, bf_ = t & 1;
    load_lds16(srcA[h][0] + ks*128, dA + bf_*32768 + h*16384);
    load_lds16(srcA[h][1] + ks*128, dA + bf_*32768 + h*16384 + 8192);
  };
  auto stB = [&](int t, int h){
    if (t >= NT) return;
    int ks = t & 7, bf_ = t & 1;
    long long eo = ((t >= 8) ? edelt : 0) + ks*128;
    load_lds16(srcB0 + h*131072 + eo,         dB + bf_*32768 + h*16384);
    load_lds16(srcB0 + h*131072 + 65536 + eo, dB + bf_*32768 + h*16384 + 8192);
  };

  const char* A0 = sm + wm*16384;
  const char* A1 = A0 + 32768;
  const char* B0 = sm + BBASE + (wn >> 1)*16384;
  const char* B1 = B0 + 32768;

  f32x4 acc[8][4];
  #pragma unroll
  for (int m = 0; m < 8; ++m)
    #pragma unroll
    for (int n = 0; n < 4; ++n) acc[m][n] = (f32x4){0.f,0.f,0.f,0.f};

  stA(0,0); stA(0,1); stB(0,0); stB(0,1); stB(1,0); stB(1,1);
  asm volatile("s_waitcnt vmcnt(4)"); SB0;
  __builtin_amdgcn_s_barrier();

  f16x8 af[4][2], bL[2][2], bH[2][2];
  #pragma unroll 1
  for (int i = 0; i < 8; ++i){
    int t0 = 2*i, t1 = t0 + 1;
    RDA(A0, 0); RDB(B0, bL, 0); stA(t1, 0);
    PH_MID; MMAC(bL, 0, 0); PH_END;
    RDB(B0, bH, 2); stA(t1, 1);
    PH_MID; MMAC(bH, 0, 2); PH_END;
    RDA(A0, 4); stB(t0+2, 0);
    PH_MID; MMAC(bH, 4, 2); PH_END;
    stB(t0+2, 1);
    if (i != 7) { asm volatile("s_waitcnt vmcnt(4)"); SB0; }
    else        { asm volatile("s_waitcnt vmcnt(0)"); SB0; }
    PH_MID; MMAC(bL, 4, 0); PH_END;
    RDA(A1, 0); RDB(B1, bL, 0); stA(t0+2, 0);
    PH_MID; MMAC(bL, 0, 0); PH_END;
    RDB(B1, bH, 2); stA(t0+2, 1);
    PH_MID; MMAC(bH, 0, 2); PH_END;
    RDA(A1, 4); stB(t1+2, 0);
    PH_MID; MMAC(bH, 4, 2); PH_END;
    stB(t1+2, 1);
    if (i != 7) { asm volatile("s_waitcnt vmcnt(4)"); SB0; }
    PH_MID; MMAC(bL, 4, 0); PH_END;
    if (i == 3){            // expert switch: fold gate-A into accumulator
      #pragma unroll
      for (int m = 0; m < 8; ++m)
        #pragma unroll
        for (int j = 0; j < 4; ++j){
          int row = wm*128 + m*16 + l4*4 + j;
          float2 g2 = ((const float2*)(sm + LG))[row];
          float r_ = g2.x / g2.y;
          #pragma unroll
          for (int n = 0; n < 4; ++n) acc[m][n][j] *= r_;
        }
    }
  }

  float bcA[4], bcB[4];
  #pragma unroll
  for (int n = 0; n < 4; ++n){
    int col = nt*256 + wn*64 + n*16 + l15;
    bcA[n] = be[(size_t)eA*DDIM + col];
    bcB[n] = be[(size_t)eB*DDIM + col];
  }
  #pragma unroll
  for (int m = 0; m < 8; ++m)
    #pragma unroll
    for (int j = 0; j < 4; ++j){
      int row = wm*128 + m*16 + l4*4 + j;
      int tk = ((const int*)(sm + LTOK))[row];
      if (tk >= 0){
        float2 g2 = ((const float2*)(sm + LG))[row];
        float* orow = out + (size_t)tk*DDIM + nt*256 + wn*64;
        #pragma unroll
        for (int n = 0; n < 4; ++n)
          orow[n*16 + l15] = g2.y*acc[m][n][j] + g2.x*bcA[n] + g2.y*bcB[n];
      }
    }
}

// ---- kexpertF: fallback (no x-f16 room): 128x128 pair-bucket GEMM, reg-staged A.
__global__ __launch_bounds__(256, 2) void kexpertF(
    const float* __restrict__ x,
    const f16* __restrict__ Wt, const float* __restrict__ be,
    float* __restrict__ out,
    const int* __restrict__ counts, const int* __restrict__ bases,
    const int* __restrict__ tile_pair, const int* __restrict__ tile_row0, const int* __restrict__ ntiles,
    const int* __restrict__ pair_tok, const float2* __restrict__ pair_g)
{
  __shared__ __align__(16) char sm[67072];
  const int ABUF = 0, BBUF = 32768, LTOK = 65536, LGOFF = 66048;
  int tile = blockIdx.x >> 2, nt = blockIdx.x & 3;
  if (tile >= *ntiles) return;
  int p = tile_pair[tile], row0 = tile_row0[tile];
  int base = bases[p], cnt = counts[p];
  int eA = p >> 4, eB = p & 15;
  int tid = threadIdx.x, lane = tid & 63;
  int w = tid >> 6, wm = w >> 1, wn = w & 1;
  if (tid < 128){
    int rr = row0 + tid; bool v = rr < cnt;
    ((int*)(sm + LTOK))[tid] = v ? pair_tok[base + rr] : -1;
    ((float2*)(sm + LGOFF))[tid] = v ? pair_g[base + rr] : make_float2(0.f, 0.f);
  }
  __syncthreads();
  const char* wb = (const char*)Wt;
  int grp = tid >> 3, gch = tid & 7;
  int swz = (gch ^ (grp & 7)) << 4;
  long long edelt = ((long long)eB - (long long)eA) * 524288;
  const char* srcB[4];
  #pragma unroll
  for (int i = 0; i < 4; ++i)
    srcB[i] = wb + (long long)eA*524288 + (size_t)(nt*128 + i*32 + grp)*1024 + swz;
  int arow = tid >> 1, ach = tid & 1;
  int tkr = ((const int*)(sm + LTOK))[arow];
  if (tkr < 0) tkr = 0;
  const float* xrow = x + (size_t)tkr*DDIM + ach*32;
  int ldst = (w << 10);
  #pragma unroll
  for (int i = 0; i < 4; ++i) load_lds16(srcB[i], sm + BBUF + i*4096 + ldst);
  {
    #pragma unroll
    for (int q2 = 0; q2 < 4; ++q2){
      float fv[8];
      *(float4*)&fv[0] = *(const float4*)(xrow + q2*8);
      *(float4*)&fv[4] = *(const float4*)(xrow + q2*8 + 4);
      f16x8 hv = pack8f(fv);
      int g = ach*4 + q2;
      *(f16x8*)(sm + ABUF + arow*128 + ((g ^ (arow & 7)) << 4)) = hv;
    }
  }
  f32x4 acc[4][4], res[4][4];
  #pragma unroll
  for (int m=0;m<4;++m)
    #pragma unroll
    for (int n=0;n<4;++n) acc[m][n] = (f32x4){0.f,0.f,0.f,0.f};
  for (int u = 0; u < 16; ++u){
    int b = u & 1;
    asm volatile("s_waitcnt vmcnt(0)" ::: "memory");
    __syncthreads();
    int un = u + 1;
    f16x8 hv[4];
    if (un < 16){
      int b2 = un & 1;
      long long aoff = (long long)(un & 7) * 128;
      long long boff = aoff + ((un >> 3) ? edelt : 0);
      #pragma unroll
      for (int i = 0; i < 4; ++i)
        load_lds16(srcB[i] + boff, sm + BBUF + b2*16384 + i*4096 + ldst);
      const float* xr = xrow + (un & 7)*64;
      #pragma unroll
      for (int q2 = 0; q2 < 4; ++q2){
        float fv[8];
        *(float4*)&fv[0] = *(const float4*)(xr + q2*8);
        *(float4*)&fv[4] = *(const float4*)(xr + q2*8 + 4);
        hv[q2] = pack8f(fv);
      }
    }
    const char* Ab = sm + ABUF + b*16384;
    const char* Bb = sm + BBUF + b*16384;
    f16x8 af2[4][2], bf2[4][2];
    #pragma unroll
    for (int m=0;m<4;++m){
      int r = wm*64 + m*16 + (lane & 15);
      af2[m][0] = readF64h(Ab, r, (lane >> 4));
      af2[m][1] = readF64h(Ab, r, 4 + (lane >> 4));
    }
    #pragma unroll
    for (int n=0;n<4;++n){
      int r = wn*64 + n*16 + (lane & 15);
      bf2[n][0] = readF64h(Bb, r, (lane >> 4));
      bf2[n][1] = readF64h(Bb, r, 4 + (lane >> 4));
    }
    #pragma unroll
    for (int m=0;m<4;++m)
      #pragma unroll
      for (int n=0;n<4;++n){
        acc[m][n] = MFMAH(af2[m][0], bf2[n][0], acc[m][n]);
        acc[m][n] = MFMAH(af2[m][1], bf2[n][1], acc[m][n]);
      }
    if (un < 16){
      int b2 = un & 1;
      #pragma unroll
      for (int q2 = 0; q2 < 4; ++q2){
        int g = ach*4 + q2;
        *(f16x8*)(sm + ABUF + b2*16384 + arow*128 + ((g ^ (arow & 7)) << 4)) = hv[q2];
      }
    }
    if (u == 7){
      const float* bev = be + (size_t)eA*DDIM + nt*128;
      float bcol[4];
      #pragma unroll
      for (int n=0;n<4;++n) bcol[n] = bev[wn*64 + n*16 + (lane & 15)];
      #pragma unroll
      for (int m=0;m<4;++m)
        #pragma unroll
        for (int j=0;j<4;++j){
          int row = wm*64 + m*16 + ((lane >> 4) << 2) + j;
          float g = ((const float2*)(sm + LGOFF))[row].x;
          #pragma unroll
          for (int n=0;n<4;++n){
            res[m][n][j] = g * (acc[m][n][j] + bcol[n]);
            acc[m][n][j] = 0.f;
          }
        }
    }
    if (u == 15){
      const float* bev = be + (size_t)eB*DDIM + nt*128;
      float bcol[4];
      #pragma unroll
      for (int n=0;n<4;++n) bcol[n] = bev[wn*64 + n*16 + (lane & 15)];
      #pragma unroll
      for (int m=0;m<4;++m)
        #pragma unroll
        for (int j=0;j<4;++j){
          int row = wm*64 + m*16 + ((lane >> 4) << 2) + j;
          int tk = ((const int*)(sm + LTOK))[row];
          float g = ((const float2*)(sm + LGOFF))[row].y;
          if (tk >= 0){
            float* orow = out + (size_t)tk*DDIM + nt*128;
            #pragma unroll
            for (int n=0;n<4;++n)
              orow[wn*64 + n*16 + (lane & 15)] = res[m][n][j] + g * (acc[m][n][j] + bcol[n]);
          }
        }
    }
  }
}

// ---- host launch --------------------------------------------------------------
extern "C" void kernel_launch(void* const* d_in, const int* in_sizes, int n_in,
                              void* d_out, int out_size, void* d_ws, size_t ws_size,
                              hipStream_t stream)
{
  const float* x   = (const float*)d_in[0];
  const float* Wg1 = (const float*)d_in[1];
  const float* bg1 = (const float*)d_in[2];
  const float* Wg2 = (const float*)d_in[3];
  const float* bg2 = (const float*)d_in[4];
  const float* We  = (const float*)d_in[5];
  const float* be  = (const float*)d_in[6];
  float* out = (float*)d_out;
  char* ws = (char*)d_ws;

  f16*  Wt          = (f16*)(ws + 0);             // 8,388,608
  f16*  W1          = (f16*)(ws + 8388608);       //   131,072
  char* Wg2f        = ws + 8519680;               //     4,096 (of 131,072 slot)
  char* CTRL        = ws + 8650752;               //     8,192
  int*  refine_cnt  = (int*)(CTRL);
  int*  ntiles      = (int*)(CTRL + 4);
  int*  counts      = (int*)(CTRL + 64);          // 256 ints
  int*  cursors     = (int*)(CTRL + 2048);        // 256 ints
  int*  bases       = (int*)(CTRL + 4096);        // 257 ints
  int2*   gate_e    = (int2*)(ws + 8658944);      // 1,048,576
  float2* gate_g    = (float2*)(ws + 9707520);    // 1,048,576
  int*  refine_list = (int*)(ws + 10756096);      //   524,288
  int*  pair_tok    = (int*)(ws + 11280384);      //   524,288
  float2* pair_g    = (float2*)(ws + 11804672);   // 1,048,576
  int*  tile_pair   = (int*)(ws + 12853248);      //    10,240
  int*  tile_row0   = (int*)(ws + 12863488);      //    10,240
  const size_t XBF_OFF = 16777216ull;
  const size_t XBF_BYTES = (size_t)NTOK * DDIM * 2;   // 134 MB (f16 x)
  bool bf16a = ws_size >= XBF_OFF + XBF_BYTES;
  f16* xbf = bf16a ? (f16*)(ws + XBF_OFF) : nullptr;

  hipMemsetAsync(CTRL, 0, 8192, stream);
  hipLaunchKernelGGL(kconv,    dim3(1041), dim3(256), 0, stream, We, Wg1, Wg2, Wt, W1, Wg2f);
  hipLaunchKernelGGL(kgate,    dim3(2048), dim3(256), 0, stream, x, W1, Wg2f, bg1, bg2,
                     xbf, gate_e, gate_g, refine_cnt, refine_list, counts);
  hipLaunchKernelGGL(krefine,  dim3(1024), dim3(128), 0, stream, x, Wg1, bg1, Wg2, bg2,
                     refine_cnt, refine_list, gate_e, gate_g, counts);
  hipLaunchKernelGGL(kscan,    dim3(1),    dim3(64),  0, stream, counts, bases, tile_pair, tile_row0, ntiles,
                     bf16a ? 256 : 128);
  hipLaunchKernelGGL(kscatter, dim3(512),  dim3(256), 0, stream, gate_e, gate_g, bases, cursors, pair_tok, pair_g);
  if (bf16a)
    hipLaunchKernelGGL(kexpert2, dim3(1408), dim3(512), 0, stream, xbf, Wt, be, out,
                       counts, bases, tile_pair, tile_row0, ntiles, pair_tok, pair_g);
  else
    hipLaunchKernelGGL(kexpertF, dim3(5120), dim3(256), 0, stream, x, Wt, be, out,
                       counts, bases, tile_pair, tile_row0, ntiles, pair_tok, pair_g);
  (void)in_sizes; (void)n_in; (void)out_size; (void)ws_size;
}

// Round 6
// 461.551 us; speedup vs baseline: 1.0454x; 1.0454x over previous
//
#include <hip/hip_runtime.h>
#include <cstdint>
#include <math.h>

// MoE top-2 of 16 experts. N=131072, D=512, H=128, E=16, O=512.  All-fp16 path:
//   kconv (We->Wt f16 [O][D], Wg1->W1 f16 [H][D], Wg2->frag-order f16, CTRL zero)
//   -> kgate (fp16 MFMA GEMM1 BK=64 + MFMA GEMM2 + fp32 softmax/top2 + x-f16 store
//             + pair histogram; margin 1e-3 flags ambiguous)
//   -> krefine (fp64 exact gating for flagged tokens, 4-way chains; patches counts)
//   -> kscatter (fused block-local scan + scatter; block 0 writes bases/tile list)
//   -> kexpert2 (pair-bucket f16 GEMM, 256 tok x 256 cols, 8-phase counted-vmcnt,
//      both operands via global_load_lds w/ pre-swizzled per-lane source;
//      gate-A folded into accumulator; single store, no atomics)

#define NTOK 131072
#define DDIM 512
#define NT 16          // K-tiles in kexpert2: 8 per expert x 2 experts

typedef _Float16 f16;
typedef f16   f16x8 __attribute__((ext_vector_type(8)));
typedef float f32x4 __attribute__((ext_vector_type(4)));

__device__ __forceinline__ void load_lds16(const void* g, void* l){
  __builtin_amdgcn_global_load_lds(
      (const __attribute__((address_space(1))) void*)(uintptr_t)g,
      (__attribute__((address_space(3))) void*)(uintptr_t)l, 16, 0, 0);
}

__device__ __forceinline__ f32x4 MFMAH(f16x8 a, f16x8 b, f32x4 c){
  return __builtin_amdgcn_mfma_f32_16x16x32_f16(a, b, c, 0, 0, 0);
}

// ---- swizzled LDS helpers -----------------------------------------------------
// 64-col f16 tile (pitch 128B): logical (row r, 16B chunk q) at r*128+((q^(r&7))<<4)
__device__ __forceinline__ f16x8 readF64h(const char* buf, int r, int q){
  return *(const f16x8*)(buf + r*128 + ((q ^ (r & 7)) << 4));
}
__device__ __forceinline__ f16x8 pack8f(const float* fv){
  f16x8 v;
  #pragma unroll
  for (int j=0;j<8;++j) v[j] = (f16)fv[j];   // RNE v_cvt_f16_f32
  return v;
}

// ---- kconv: We [E][D][O] f32 -> Wt f16 [E][O][D]; Wg1 [D][H] f32 -> W1 f16 [H][D];
//             Wg2 [H][E] f32 -> Wg2f fragment-order f16; CTRL zeroing.
__global__ void kconv(const float* __restrict__ We, const float* __restrict__ Wg1,
                      const float* __restrict__ Wg2,
                      f16* __restrict__ Wt, f16* __restrict__ W1, char* __restrict__ Wg2f,
                      int* __restrict__ ctrl){
  __shared__ float sh[64*65];
  int bx = blockIdx.x, tid = threadIdx.x;
  if (bx < 1024){
    int e = bx >> 6, dt = (bx >> 3) & 7, ot = bx & 7;
    const float* src = We + (size_t)e*262144 + (size_t)dt*64*512 + ot*64;
    #pragma unroll
    for (int it=0; it<16; ++it){ int idx = it*256+tid; int dl = idx>>6, ol = idx&63;
      sh[dl*65+ol] = src[dl*512+ol]; }
    __syncthreads();
    f16* dst = Wt + (size_t)e*262144 + (size_t)ot*64*512 + dt*64;
    #pragma unroll
    for (int it=0; it<16; ++it){ int idx = it*256+tid; int ol = idx>>6, dl = idx&63;
      dst[(size_t)ol*512+dl] = (f16)sh[dl*65+ol]; }
  } else if (bx < 1040){
    int q = bx - 1024;
    int dt = q >> 1, ht = q & 1;
    const float* src = Wg1 + (size_t)dt*64*128 + ht*64;
    #pragma unroll
    for (int it=0; it<16; ++it){ int idx = it*256+tid; int dl = idx>>6, ol = idx&63;
      sh[dl*65+ol] = src[dl*128+ol]; }
    __syncthreads();
    #pragma unroll
    for (int it=0; it<16; ++it){ int idx = it*256+tid; int ol = idx>>6, dl = idx&63;
      W1[(size_t)(ht*64+ol)*512 + dt*64+dl] = (f16)sh[dl*65+ol]; }
  } else {
    // Wg2 -> MFMA B-fragment order: frag[ks][lane][j] = Wg2[ks*32+(lane>>4)*8+j][lane&15]
    int ks = tid >> 6, l = tid & 63;
    int col = l & 15, kb = ks*32 + ((l >> 4) << 3);
    f16x8 v;
    #pragma unroll
    for (int j=0;j<8;++j) v[j] = (f16)Wg2[(kb+j)*16 + col];
    *(f16x8*)(Wg2f + (ks*64+l)*16) = v;
    #pragma unroll
    for (int i = 0; i < 8; ++i) ctrl[tid + i*256] = 0;   // zero CTRL (8KB)
  }
}

// ---- kgate: fp16 gating (BK=64) + x-f16 producer + pair histogram. 64 tok/block.
__global__ __launch_bounds__(256) void kgate(
    const float* __restrict__ x, const f16* __restrict__ W1, const char* __restrict__ Wg2f,
    const float* __restrict__ bg1, const float* __restrict__ bg2,
    f16* __restrict__ xbf,
    int2* __restrict__ gate_e, float2* __restrict__ gate_g,
    int* __restrict__ refine_cnt, int* __restrict__ refine_list, int* __restrict__ counts)
{
  __shared__ __align__(16) char sm[49152];
  const int AOFF = 0;       // A dbuf 2x8KB: [0,8K),[8K,16K)
  const int BOFF = 16384;   // B dbuf 2x16KB: [16K,32K),[32K,48K)
  int tid = threadIdx.x, bid = blockIdx.x;
  int lane = tid & 63, w = tid >> 6, wm = w >> 1, wn = w & 1;
  int l15 = lane & 15, l4 = lane >> 4;
  int t0 = bid * 64;
  int ar = tid >> 2, acq = tid & 3;
  const float* xrow = x + (size_t)(t0 + ar) * DDIM;
  char* xbfb = (char*)xbf;
  f32x4 acc[2][4];
  #pragma unroll
  for (int n=0;n<4;++n){
    float bb = bg1[wn*64 + n*16 + l15];
    f32x4 z = {bb, bb, bb, bb};
    acc[0][n] = z; acc[1][n] = z;
  }
  // A stage: row ar, 16 cols at acq*16; swizzled chunks acq*2, acq*2+1
  auto stageA = [&](int ks, char* abuf){
    float fv[16];
    #pragma unroll
    for (int q=0;q<4;++q) *(float4*)&fv[q*4] = *(const float4*)(xrow + ks*64 + acq*16 + q*4);
    f16x8 h0 = pack8f(fv), h1 = pack8f(fv+8);
    *(f16x8*)(abuf + ar*128 + (((acq*2)   ^ (ar & 7)) << 4)) = h0;
    *(f16x8*)(abuf + ar*128 + (((acq*2+1) ^ (ar & 7)) << 4)) = h1;
    if (xbf){
      char* xd = xbfb + (size_t)(t0+ar)*1024 + ks*128 + acq*32;
      *(f16x8*)xd = h0; *(f16x8*)(xd+16) = h1;
    }
  };
  // B stage [128 h][64 k] 16KB via gload_lds, pre-swizzled source; W1 pitch 1024B
  auto stageB = [&](int ks, char* lds){
    const char* gb = (const char*)W1 + ks*128;
    #pragma unroll
    for (int i = 0; i < 4; ++i){
      int lin = i*4096 + tid*16;
      int r = lin >> 7, g = (lin >> 4) & 7;
      load_lds16(gb + r*1024 + ((g ^ (r & 7)) << 4), lds + i*4096 + ((tid >> 6) << 10));
    }
  };
  stageB(0, sm + BOFF); stageA(0, sm + AOFF);
  for (int ks = 0; ks < 8; ++ks){
    int b = ks & 1;
    asm volatile("s_waitcnt vmcnt(0)" ::: "memory");
    __syncthreads();
    if (ks < 7) stageB(ks+1, sm + BOFF + (b^1)*16384);
    const char* Ab = sm + AOFF + b*8192;
    const char* Bb = sm + BOFF + b*16384;
    f16x8 ah[2][2], bh[4][2];
    #pragma unroll
    for (int m=0;m<2;++m)
      #pragma unroll
      for (int kf=0;kf<2;++kf) ah[m][kf] = readF64h(Ab, wm*32 + m*16 + l15, kf*4 + l4);
    #pragma unroll
    for (int n=0;n<4;++n)
      #pragma unroll
      for (int kf=0;kf<2;++kf) bh[n][kf] = readF64h(Bb, wn*64 + n*16 + l15, kf*4 + l4);
    #pragma unroll
    for (int m=0;m<2;++m)
      #pragma unroll
      for (int n=0;n<4;++n){
        acc[m][n] = MFMAH(ah[m][0], bh[n][0], acc[m][n]);
        acc[m][n] = MFMAH(ah[m][1], bh[n][1], acc[m][n]);
      }
    if (ks < 7) stageA(ks+1, sm + AOFF + (b^1)*8192);
  }
  __syncthreads();
  // prefetch Wg2 B-fragments (lane-indexed, same for all waves)
  uint4 wgf[4];
  #pragma unroll
  for (int ksq=0; ksq<4; ++ksq) wgf[ksq] = *(const uint4*)(Wg2f + (ksq*64+lane)*16);
  // GELU (exact erf) -> h f32 [64][132] at sm+0 (A/B bufs dead)
  float* hl = (float*)sm;
  #pragma unroll
  for (int m=0;m<2;++m)
    #pragma unroll
    for (int n=0;n<4;++n)
      #pragma unroll
      for (int j=0;j<4;++j){
        int row = wm*32 + m*16 + (l4 << 2) + j;
        int col = wn*64 + n*16 + l15;
        float uv = acc[m][n][j];
        hl[row*132 + col] = 0.5f * uv * (1.0f + erff(uv * 0.70710678118654752f));
      }
  __syncthreads();
  // GEMM2 via MFMA: logits[64][16]; wave w -> token rows w*16..+15
  {
    float bb2 = bg2[l15];
    f32x4 acc2 = {bb2, bb2, bb2, bb2};
    #pragma unroll
    for (int ksq=0; ksq<4; ++ksq){
      const float* hp = (const float*)sm + (w*16 + l15)*132 + ksq*32 + l4*8;
      f16x8 afr;
      #pragma unroll
      for (int j=0;j<8;++j) afr[j] = (f16)hp[j];
      acc2 = MFMAH(afr, *(const f16x8*)&wgf[ksq], acc2);
    }
    float* ll = (float*)(sm + 36864);
    #pragma unroll
    for (int j=0;j<4;++j) ll[(w*16 + l4*4 + j)*16 + l15] = acc2[j];
  }
  int* hist = (int*)(sm + 40960);
  hist[tid] = 0;
  __syncthreads();
  if (tid < 64){
    int t = t0 + tid;
    const float* l = (const float*)(sm + 36864) + tid*16;
    float b1 = -1e30f, b2 = -1e30f, b3 = -1e30f; int e1 = 0, e2 = 0;
    #pragma unroll
    for (int e = 0; e < 16; ++e){
      float v = l[e];
      if (v > b1){ b3 = b2; b2 = b1; e2 = e1; b1 = v; e1 = e; }
      else if (v > b2){ b3 = b2; b2 = v; e2 = e; }
      else if (v > b3){ b3 = v; }
    }
    float s = 0.f;
    #pragma unroll
    for (int e = 0; e < 16; ++e) s += expf(l[e] - b1);
    float inv = 1.f / s;
    gate_e[t] = make_int2(e1, e2);
    gate_g[t] = make_float2(inv + 1e-4f, expf(b2 - b1) * inv + 1e-4f);
    if (b2 - b3 < 1e-3f){            // fp16-path margin: flag ambiguous top2/top3
      int pos = atomicAdd(refine_cnt, 1);
      refine_list[pos] = t;
    }
    int pa = min(e1, e2), pb = max(e1, e2);
    atomicAdd(&hist[pa*16 + pb], 1);
  }
  __syncthreads();
  if (hist[tid]) atomicAdd(&counts[tid], hist[tid]);
}

// ---- krefine: exact fp64 gating for flagged tokens (4-way chains); patches counts.
__global__ __launch_bounds__(128) void krefine(
    const float* __restrict__ x, const float* __restrict__ Wg1, const float* __restrict__ bg1,
    const float* __restrict__ Wg2, const float* __restrict__ bg2,
    const int* __restrict__ refine_cnt, const int* __restrict__ refine_list,
    int2* __restrict__ gate_e, float2* __restrict__ gate_g, int* __restrict__ counts)
{
  __shared__ float  xs[512];
  __shared__ double hd[128];
  __shared__ double ld[16];
  int tid = threadIdx.x;
  int rc = *refine_cnt;
  for (int i = blockIdx.x; i < rc; i += gridDim.x){
    __syncthreads();
    int t = refine_list[i];
    *(float4*)(xs + tid*4) = *(const float4*)(x + (size_t)t*DDIM + tid*4);
    __syncthreads();
    double a0=0.0, a1=0.0, a2=0.0, a3=0.0;
    for (int d = 0; d < 512; d += 4){
      a0 += (double)xs[d]   * (double)Wg1[(d)*128 + tid];
      a1 += (double)xs[d+1] * (double)Wg1[(d+1)*128 + tid];
      a2 += (double)xs[d+2] * (double)Wg1[(d+2)*128 + tid];
      a3 += (double)xs[d+3] * (double)Wg1[(d+3)*128 + tid];
    }
    double a = (double)bg1[tid] + ((a0+a1)+(a2+a3));
    hd[tid] = 0.5 * a * (1.0 + erf(a * 0.70710678118654752440));
    __syncthreads();
    if (tid < 16){
      double s0=0.0, s1=0.0;
      for (int k = 0; k < 128; k += 2){
        s0 += hd[k]   * (double)Wg2[(k)*16 + tid];
        s1 += hd[k+1] * (double)Wg2[(k+1)*16 + tid];
      }
      ld[tid] = (double)bg2[tid] + s0 + s1;
    }
    __syncthreads();
    if (tid == 0){
      int2 olde = gate_e[t];
      double b1 = -1e300, b2 = -1e300; int e1 = 0, e2 = 0;
      for (int e = 0; e < 16; ++e){
        double v = ld[e];
        if (v > b1){ b2 = b1; e2 = e1; b1 = v; e1 = e; }
        else if (v > b2){ b2 = v; e2 = e; }
      }
      double s = 0.0;
      for (int e = 0; e < 16; ++e) s += exp(ld[e] - b1);
      double inv = 1.0 / s;
      int oldp = min(olde.x, olde.y)*16 + max(olde.x, olde.y);
      int newp = min(e1, e2)*16 + max(e1, e2);
      if (oldp != newp){ atomicSub(&counts[oldp], 1); atomicAdd(&counts[newp], 1); }
      gate_e[t] = make_int2(e1, e2);
      gate_g[t] = make_float2((float)(inv + 1e-4), (float)(exp(b2 - b1) * inv + 1e-4));
    }
  }
}

// ---- kscatter: fused scan + scatter. Each block computes the 256-pair prefix scan
// locally (wave 0); block 0 additionally writes global bases + tile list + ntiles.
__global__ __launch_bounds__(256) void kscatter(
    const int2* __restrict__ gate_e, const float2* __restrict__ gate_g,
    const int* __restrict__ counts,
    int* __restrict__ bases, int* __restrict__ cursors,
    int* __restrict__ tile_pair, int* __restrict__ tile_row0, int* __restrict__ ntiles,
    int* __restrict__ pair_tok, float2* __restrict__ pair_g, int ts)
{
  __shared__ int h[256];
  __shared__ int gb[256];
  __shared__ int bl[257];
  int tid = threadIdx.x;
  h[tid] = 0;
  if (tid < 64){
    int l = tid;
    int4 c = *(const int4*)(counts + l*4);
    int s = c.x + c.y + c.z + c.w;
    int ps = s;
    #pragma unroll
    for (int d = 1; d < 64; d <<= 1){ int v = __shfl_up(ps, d); if (l >= d) ps += v; }
    int ex = ps - s;
    bl[4*l+0] = ex;
    bl[4*l+1] = ex + c.x;
    bl[4*l+2] = ex + c.x + c.y;
    bl[4*l+3] = ex + c.x + c.y + c.z;
    if (l == 63) bl[256] = ex + s;
    if (blockIdx.x == 0){
      *(int4*)(bases + 4*l) = make_int4(bl[4*l], bl[4*l+1], bl[4*l+2], bl[4*l+3]);
      if (l == 63) bases[256] = ex + s;
      int t0 = (c.x + ts-1)/ts, t1 = (c.y + ts-1)/ts, t2 = (c.z + ts-1)/ts, t3 = (c.w + ts-1)/ts;
      int tsum = t0 + t1 + t2 + t3;
      int pt = tsum;
      #pragma unroll
      for (int d = 1; d < 64; d <<= 1){ int v = __shfl_up(pt, d); if (l >= d) pt += v; }
      int ext = pt - tsum;
      if (l == 63) *ntiles = ext + tsum;
      int tb = ext;
      int cc[4] = {c.x, c.y, c.z, c.w};
      #pragma unroll
      for (int j = 0; j < 4; ++j){
        int pp = 4*l + j;
        for (int r = 0; r < cc[j]; r += ts){ tile_pair[tb] = pp; tile_row0[tb] = r; ++tb; }
      }
    }
  }
  __syncthreads();
  int t = blockIdx.x*256 + tid;
  int2 ee = gate_e[t]; float2 gg = gate_g[t];
  int a, b; float ga, gbv;
  if (ee.x < ee.y){ a = ee.x; b = ee.y; ga = gg.x; gbv = gg.y; }
  else            { a = ee.y; b = ee.x; ga = gg.y; gbv = gg.x; }
  int p = a*16 + b;
  int off = atomicAdd(&h[p], 1);
  __syncthreads();
  if (h[tid]) gb[tid] = bl[tid] + atomicAdd(&cursors[tid], h[tid]);
  __syncthreads();
  int slot = gb[p] + off;
  pair_tok[slot] = t;
  pair_g[slot] = make_float2(ga, gbv);
}

// ======== kexpert2: 256x256 pair-bucket GEMM, 8-phase counted-vmcnt schedule ====
#define SB0 __builtin_amdgcn_sched_barrier(0)
#define PH_MID do{ __builtin_amdgcn_s_barrier(); \
                   asm volatile("s_waitcnt lgkmcnt(0)"); SB0; }while(0)
#define PH_END do{ SB0; __builtin_amdgcn_s_barrier(); }while(0)

#define RDA(hp, mb) do{ \
  _Pragma("unroll") for (int m_=0;m_<4;++m_){ \
    int r_ = ((mb)+m_)*16 + l15; \
    af[m_][0] = readF64h(hp, r_, l4); \
    af[m_][1] = readF64h(hp, r_, 4+l4); }}while(0)
#define RDB(hp, bv, nb) do{ \
  _Pragma("unroll") for (int n_=0;n_<2;++n_){ \
    int r_ = bln + ((nb)+n_)*16 + l15; \
    bv[n_][0] = readF64h(hp, r_, l4); \
    bv[n_][1] = readF64h(hp, r_, 4+l4); }}while(0)
#define MMAC(bv, mb, nb) do{ \
  __builtin_amdgcn_s_setprio(1); \
  _Pragma("unroll") for (int m_=0;m_<4;++m_){ \
    _Pragma("unroll") for (int n_=0;n_<2;++n_){ \
      acc[(mb)+m_][(nb)+n_] = MFMAH(af[m_][0], bv[n_][0], acc[(mb)+m_][(nb)+n_]); \
      acc[(mb)+m_][(nb)+n_] = MFMAH(af[m_][1], bv[n_][1], acc[(mb)+m_][(nb)+n_]); }} \
  __builtin_amdgcn_s_setprio(0); \
}while(0)

__global__ __launch_bounds__(512, 2) void kexpert2(
    const f16* __restrict__ xbf, const f16* __restrict__ Wt, const float* __restrict__ be,
    float* __restrict__ out,
    const int* __restrict__ counts, const int* __restrict__ bases,
    const int* __restrict__ tile_pair, const int* __restrict__ tile_row0, const int* __restrict__ ntiles,
    const int* __restrict__ pair_tok, const float2* __restrict__ pair_g)
{
  __shared__ __align__(16) char sm[134144];
  const int BBASE = 65536, LTOK = 131072, LG = 132096;
  int bid = blockIdx.x;
  int tile = ((bid >> 4) << 3) | (bid & 7);   // col-block pair shares XCD
  int nt = (bid >> 3) & 1;
  if (tile >= *ntiles) return;
  int p = tile_pair[tile], row0 = tile_row0[tile];
  int base = bases[p], cnt = counts[p];
  int eA = p >> 4, eB = p & 15;
  int tid = threadIdx.x, lane = tid & 63, w = tid >> 6;
  int wm = w >> 2, wn = w & 3;
  int l15 = lane & 15, l4 = lane >> 4;
  int bln = (wn & 1) * 64;
  if (tid < 256){
    int rr = row0 + tid; bool v = rr < cnt;
    ((int*)(sm + LTOK))[tid] = v ? pair_tok[base + rr] : -1;
    ((float2*)(sm + LG))[tid] = v ? pair_g[base + rr] : make_float2(0.f, 1.f);
  }
  __syncthreads();

  int rr0 = tid >> 3;
  int sw = ((tid & 7) ^ (rr0 & 7)) << 4;
  const char* xb = (const char*)xbf;
  const char* srcA[2][2];
  #pragma unroll
  for (int h = 0; h < 2; ++h)
    #pragma unroll
    for (int i = 0; i < 2; ++i){
      int tk = ((const int*)(sm + LTOK))[h*128 + i*64 + rr0];
      if (tk < 0) tk = 0;
      srcA[h][i] = xb + (size_t)tk*1024 + sw;
    }
  const char* srcB0 = (const char*)Wt + (size_t)eA*524288 + (size_t)(nt*256 + rr0)*1024 + sw;
  long long edelt = ((long long)eB - eA) * 524288;
  char* dA = sm + w*1024;
  char* dB = sm + BBASE + w*1024;

  auto stA = [&](int t, int h){
    if (t >= NT) return;
    int ks = t & 7, bf_ = t & 1;
    load_lds16(srcA[h][0] + ks*128, dA + bf_*32768 + h*16384);
    load_lds16(srcA[h][1] + ks*128, dA + bf_*32768 + h*16384 + 8192);
  };
  auto stB = [&](int t, int h){
    if (t >= NT) return;
    int ks = t & 7, bf_ = t & 1;
    long long eo = ((t >= 8) ? edelt : 0) + ks*128;
    load_lds16(srcB0 + h*131072 + eo,         dB + bf_*32768 + h*16384);
    load_lds16(srcB0 + h*131072 + 65536 + eo, dB + bf_*32768 + h*16384 + 8192);
  };

  const char* A0 = sm + wm*16384;
  const char* A1 = A0 + 32768;
  const char* B0 = sm + BBASE + (wn >> 1)*16384;
  const char* B1 = B0 + 32768;

  f32x4 acc[8][4];
  #pragma unroll
  for (int m = 0; m < 8; ++m)
    #pragma unroll
    for (int n = 0; n < 4; ++n) acc[m][n] = (f32x4){0.f,0.f,0.f,0.f};

  stA(0,0); stA(0,1); stB(0,0); stB(0,1); stB(1,0); stB(1,1);
  asm volatile("s_waitcnt vmcnt(4)"); SB0;
  __builtin_amdgcn_s_barrier();

  f16x8 af[4][2], bL[2][2], bH[2][2];
  #pragma unroll 1
  for (int i = 0; i < 8; ++i){
    int t0 = 2*i, t1 = t0 + 1;
    RDA(A0, 0); RDB(B0, bL, 0); stA(t1, 0);
    PH_MID; MMAC(bL, 0, 0); PH_END;
    RDB(B0, bH, 2); stA(t1, 1);
    PH_MID; MMAC(bH, 0, 2); PH_END;
    RDA(A0, 4); stB(t0+2, 0);
    PH_MID; MMAC(bH, 4, 2); PH_END;
    stB(t0+2, 1);
    if (i != 7) { asm volatile("s_waitcnt vmcnt(4)"); SB0; }
    else        { asm volatile("s_waitcnt vmcnt(0)"); SB0; }
    PH_MID; MMAC(bL, 4, 0); PH_END;
    RDA(A1, 0); RDB(B1, bL, 0); stA(t0+2, 0);
    PH_MID; MMAC(bL, 0, 0); PH_END;
    RDB(B1, bH, 2); stA(t0+2, 1);
    PH_MID; MMAC(bH, 0, 2); PH_END;
    RDA(A1, 4); stB(t1+2, 0);
    PH_MID; MMAC(bH, 4, 2); PH_END;
    stB(t1+2, 1);
    if (i != 7) { asm volatile("s_waitcnt vmcnt(4)"); SB0; }
    PH_MID; MMAC(bL, 4, 0); PH_END;
    if (i == 3){            // expert switch: fold gate-A into accumulator
      #pragma unroll
      for (int m = 0; m < 8; ++m)
        #pragma unroll
        for (int j = 0; j < 4; ++j){
          int row = wm*128 + m*16 + l4*4 + j;
          float2 g2 = ((const float2*)(sm + LG))[row];
          float r_ = g2.x / g2.y;
          #pragma unroll
          for (int n = 0; n < 4; ++n) acc[m][n][j] *= r_;
        }
    }
  }

  float bcA[4], bcB[4];
  #pragma unroll
  for (int n = 0; n < 4; ++n){
    int col = nt*256 + wn*64 + n*16 + l15;
    bcA[n] = be[(size_t)eA*DDIM + col];
    bcB[n] = be[(size_t)eB*DDIM + col];
  }
  #pragma unroll
  for (int m = 0; m < 8; ++m)
    #pragma unroll
    for (int j = 0; j < 4; ++j){
      int row = wm*128 + m*16 + l4*4 + j;
      int tk = ((const int*)(sm + LTOK))[row];
      if (tk >= 0){
        float2 g2 = ((const float2*)(sm + LG))[row];
        float* orow = out + (size_t)tk*DDIM + nt*256 + wn*64;
        #pragma unroll
        for (int n = 0; n < 4; ++n)
          orow[n*16 + l15] = g2.y*acc[m][n][j] + g2.x*bcA[n] + g2.y*bcB[n];
      }
    }
}

// ---- kexpertF: fallback (no x-f16 room): 128x128 pair-bucket GEMM, reg-staged A.
__global__ __launch_bounds__(256, 2) void kexpertF(
    const float* __restrict__ x,
    const f16* __restrict__ Wt, const float* __restrict__ be,
    float* __restrict__ out,
    const int* __restrict__ counts, const int* __restrict__ bases,
    const int* __restrict__ tile_pair, const int* __restrict__ tile_row0, const int* __restrict__ ntiles,
    const int* __restrict__ pair_tok, const float2* __restrict__ pair_g)
{
  __shared__ __align__(16) char sm[67072];
  const int ABUF = 0, BBUF = 32768, LTOK = 65536, LGOFF = 66048;
  int tile = blockIdx.x >> 2, nt = blockIdx.x & 3;
  if (tile >= *ntiles) return;
  int p = tile_pair[tile], row0 = tile_row0[tile];
  int base = bases[p], cnt = counts[p];
  int eA = p >> 4, eB = p & 15;
  int tid = threadIdx.x, lane = tid & 63;
  int w = tid >> 6, wm = w >> 1, wn = w & 1;
  if (tid < 128){
    int rr = row0 + tid; bool v = rr < cnt;
    ((int*)(sm + LTOK))[tid] = v ? pair_tok[base + rr] : -1;
    ((float2*)(sm + LGOFF))[tid] = v ? pair_g[base + rr] : make_float2(0.f, 0.f);
  }
  __syncthreads();
  const char* wb = (const char*)Wt;
  int grp = tid >> 3, gch = tid & 7;
  int swz = (gch ^ (grp & 7)) << 4;
  long long edelt = ((long long)eB - (long long)eA) * 524288;
  const char* srcB[4];
  #pragma unroll
  for (int i = 0; i < 4; ++i)
    srcB[i] = wb + (long long)eA*524288 + (size_t)(nt*128 + i*32 + grp)*1024 + swz;
  int arow = tid >> 1, ach = tid & 1;
  int tkr = ((const int*)(sm + LTOK))[arow];
  if (tkr < 0) tkr = 0;
  const float* xrow = x + (size_t)tkr*DDIM + ach*32;
  int ldst = (w << 10);
  #pragma unroll
  for (int i = 0; i < 4; ++i) load_lds16(srcB[i], sm + BBUF + i*4096 + ldst);
  {
    #pragma unroll
    for (int q2 = 0; q2 < 4; ++q2){
      float fv[8];
      *(float4*)&fv[0] = *(const float4*)(xrow + q2*8);
      *(float4*)&fv[4] = *(const float4*)(xrow + q2*8 + 4);
      f16x8 hv = pack8f(fv);
      int g = ach*4 + q2;
      *(f16x8*)(sm + ABUF + arow*128 + ((g ^ (arow & 7)) << 4)) = hv;
    }
  }
  f32x4 acc[4][4], res[4][4];
  #pragma unroll
  for (int m=0;m<4;++m)
    #pragma unroll
    for (int n=0;n<4;++n) acc[m][n] = (f32x4){0.f,0.f,0.f,0.f};
  for (int u = 0; u < 16; ++u){
    int b = u & 1;
    asm volatile("s_waitcnt vmcnt(0)" ::: "memory");
    __syncthreads();
    int un = u + 1;
    f16x8 hv[4];
    if (un < 16){
      int b2 = un & 1;
      long long aoff = (long long)(un & 7) * 128;
      long long boff = aoff + ((un >> 3) ? edelt : 0);
      #pragma unroll
      for (int i = 0; i < 4; ++i)
        load_lds16(srcB[i] + boff, sm + BBUF + b2*16384 + i*4096 + ldst);
      const float* xr = xrow + (un & 7)*64;
      #pragma unroll
      for (int q2 = 0; q2 < 4; ++q2){
        float fv[8];
        *(float4*)&fv[0] = *(const float4*)(xr + q2*8);
        *(float4*)&fv[4] = *(const float4*)(xr + q2*8 + 4);
        hv[q2] = pack8f(fv);
      }
    }
    const char* Ab = sm + ABUF + b*16384;
    const char* Bb = sm + BBUF + b*16384;
    f16x8 af2[4][2], bf2[4][2];
    #pragma unroll
    for (int m=0;m<4;++m){
      int r = wm*64 + m*16 + (lane & 15);
      af2[m][0] = readF64h(Ab, r, (lane >> 4));
      af2[m][1] = readF64h(Ab, r, 4 + (lane >> 4));
    }
    #pragma unroll
    for (int n=0;n<4;++n){
      int r = wn*64 + n*16 + (lane & 15);
      bf2[n][0] = readF64h(Bb, r, (lane >> 4));
      bf2[n][1] = readF64h(Bb, r, 4 + (lane >> 4));
    }
    #pragma unroll
    for (int m=0;m<4;++m)
      #pragma unroll
      for (int n=0;n<4;++n){
        acc[m][n] = MFMAH(af2[m][0], bf2[n][0], acc[m][n]);
        acc[m][n] = MFMAH(af2[m][1], bf2[n][1], acc[m][n]);
      }
    if (un < 16){
      int b2 = un & 1;
      #pragma unroll
      for (int q2 = 0; q2 < 4; ++q2){
        int g = ach*4 + q2;
        *(f16x8*)(sm + ABUF + b2*16384 + arow*128 + ((g ^ (arow & 7)) << 4)) = hv[q2];
      }
    }
    if (u == 7){
      const float* bev = be + (size_t)eA*DDIM + nt*128;
      float bcol[4];
      #pragma unroll
      for (int n=0;n<4;++n) bcol[n] = bev[wn*64 + n*16 + (lane & 15)];
      #pragma unroll
      for (int m=0;m<4;++m)
        #pragma unroll
        for (int j=0;j<4;++j){
          int row = wm*64 + m*16 + ((lane >> 4) << 2) + j;
          float g = ((const float2*)(sm + LGOFF))[row].x;
          #pragma unroll
          for (int n=0;n<4;++n){
            res[m][n][j] = g * (acc[m][n][j] + bcol[n]);
            acc[m][n][j] = 0.f;
          }
        }
    }
    if (u == 15){
      const float* bev = be + (size_t)eB*DDIM + nt*128;
      float bcol[4];
      #pragma unroll
      for (int n=0;n<4;++n) bcol[n] = bev[wn*64 + n*16 + (lane & 15)];
      #pragma unroll
      for (int m=0;m<4;++m)
        #pragma unroll
        for (int j=0;j<4;++j){
          int row = wm*64 + m*16 + ((lane >> 4) << 2) + j;
          int tk = ((const int*)(sm + LTOK))[row];
          float g = ((const float2*)(sm + LGOFF))[row].y;
          if (tk >= 0){
            float* orow = out + (size_t)tk*DDIM + nt*128;
            #pragma unroll
            for (int n=0;n<4;++n)
              orow[wn*64 + n*16 + (lane & 15)] = res[m][n][j] + g * (acc[m][n][j] + bcol[n]);
          }
        }
    }
  }
}

// ---- host launch --------------------------------------------------------------
extern "C" void kernel_launch(void* const* d_in, const int* in_sizes, int n_in,
                              void* d_out, int out_size, void* d_ws, size_t ws_size,
                              hipStream_t stream)
{
  const float* x   = (const float*)d_in[0];
  const float* Wg1 = (const float*)d_in[1];
  const float* bg1 = (const float*)d_in[2];
  const float* Wg2 = (const float*)d_in[3];
  const float* bg2 = (const float*)d_in[4];
  const float* We  = (const float*)d_in[5];
  const float* be  = (const float*)d_in[6];
  float* out = (float*)d_out;
  char* ws = (char*)d_ws;

  f16*  Wt          = (f16*)(ws + 0);             // 8,388,608
  f16*  W1          = (f16*)(ws + 8388608);       //   131,072
  char* Wg2f        = ws + 8519680;               //     4,096 (of 131,072 slot)
  char* CTRL        = ws + 8650752;               //     8,192
  int*  refine_cnt  = (int*)(CTRL);
  int*  ntiles      = (int*)(CTRL + 4);
  int*  counts      = (int*)(CTRL + 64);          // 256 ints
  int*  cursors     = (int*)(CTRL + 2048);        // 256 ints
  int*  bases       = (int*)(CTRL + 4096);        // 257 ints
  int2*   gate_e    = (int2*)(ws + 8658944);      // 1,048,576
  float2* gate_g    = (float2*)(ws + 9707520);    // 1,048,576
  int*  refine_list = (int*)(ws + 10756096);      //   524,288
  int*  pair_tok    = (int*)(ws + 11280384);      //   524,288
  float2* pair_g    = (float2*)(ws + 11804672);   // 1,048,576
  int*  tile_pair   = (int*)(ws + 12853248);      //    10,240
  int*  tile_row0   = (int*)(ws + 12863488);      //    10,240
  const size_t XBF_OFF = 16777216ull;
  const size_t XBF_BYTES = (size_t)NTOK * DDIM * 2;   // 134 MB (f16 x)
  bool bf16a = ws_size >= XBF_OFF + XBF_BYTES;
  f16* xbf = bf16a ? (f16*)(ws + XBF_OFF) : nullptr;

  hipLaunchKernelGGL(kconv,    dim3(1041), dim3(256), 0, stream, We, Wg1, Wg2, Wt, W1, Wg2f,
                     (int*)CTRL);
  hipLaunchKernelGGL(kgate,    dim3(2048), dim3(256), 0, stream, x, W1, Wg2f, bg1, bg2,
                     xbf, gate_e, gate_g, refine_cnt, refine_list, counts);
  hipLaunchKernelGGL(krefine,  dim3(512),  dim3(128), 0, stream, x, Wg1, bg1, Wg2, bg2,
                     refine_cnt, refine_list, gate_e, gate_g, counts);
  hipLaunchKernelGGL(kscatter, dim3(512),  dim3(256), 0, stream, gate_e, gate_g, counts,
                     bases, cursors, tile_pair, tile_row0, ntiles, pair_tok, pair_g,
                     bf16a ? 256 : 128);
  if (bf16a)
    hipLaunchKernelGGL(kexpert2, dim3(1408), dim3(512), 0, stream, xbf, Wt, be, out,
                       counts, bases, tile_pair, tile_row0, ntiles, pair_tok, pair_g);
  else
    hipLaunchKernelGGL(kexpertF, dim3(5120), dim3(256), 0, stream, x, Wt, be, out,
                       counts, bases, tile_pair, tile_row0, ntiles, pair_tok, pair_g);
  (void)in_sizes; (void)n_in; (void)out_size; (void)ws_size;
}

// Round 7
// 460.956 us; speedup vs baseline: 1.0468x; 1.0013x over previous
//
#include <hip/hip_runtime.h>
#include <cstdint>
#include <math.h>

// MoE top-2 of 16 experts. N=131072, D=512, H=128, E=16, O=512.  All-fp16 path:
//   kconv (We->Wt f16 [O][D], Wg1->W1 f16 [H][D], Wg2->frag-order f16, CTRL zero)
//   -> kgate (128 tok/block: fp16 MFMA GEMM1 BK=64 + MFMA GEMM2 + fp32 softmax/top2
//             + x-f16 store + pair histogram; margin 1e-3 flags ambiguous)
//   -> krefine (fp64 exact gating for flagged tokens, 4-way chains; patches counts)
//   -> kscatter (fused block-local scan + scatter; block 0 writes bases/tile list)
//   -> kexpert2 (pair-bucket f16 GEMM, 256 tok x 256 cols, 8-phase counted-vmcnt,
//      both operands via global_load_lds w/ pre-swizzled per-lane source;
//      gate-A folded into accumulator; single store, no atomics)

#define NTOK 131072
#define DDIM 512
#define NT 16          // K-tiles in kexpert2: 8 per expert x 2 experts

typedef _Float16 f16;
typedef f16   f16x8 __attribute__((ext_vector_type(8)));
typedef float f32x4 __attribute__((ext_vector_type(4)));

__device__ __forceinline__ void load_lds16(const void* g, void* l){
  __builtin_amdgcn_global_load_lds(
      (const __attribute__((address_space(1))) void*)(uintptr_t)g,
      (__attribute__((address_space(3))) void*)(uintptr_t)l, 16, 0, 0);
}

__device__ __forceinline__ f32x4 MFMAH(f16x8 a, f16x8 b, f32x4 c){
  return __builtin_amdgcn_mfma_f32_16x16x32_f16(a, b, c, 0, 0, 0);
}

// ---- swizzled LDS helpers -----------------------------------------------------
// 64-col f16 tile (pitch 128B): logical (row r, 16B chunk q) at r*128+((q^(r&7))<<4)
__device__ __forceinline__ f16x8 readF64h(const char* buf, int r, int q){
  return *(const f16x8*)(buf + r*128 + ((q ^ (r & 7)) << 4));
}
__device__ __forceinline__ f16x8 pack8f(const float* fv){
  f16x8 v;
  #pragma unroll
  for (int j=0;j<8;++j) v[j] = (f16)fv[j];   // RNE v_cvt_f16_f32
  return v;
}

// ---- kconv: We [E][D][O] f32 -> Wt f16 [E][O][D]; Wg1 [D][H] f32 -> W1 f16 [H][D];
//             Wg2 [H][E] f32 -> Wg2f fragment-order f16; CTRL zeroing.
__global__ void kconv(const float* __restrict__ We, const float* __restrict__ Wg1,
                      const float* __restrict__ Wg2,
                      f16* __restrict__ Wt, f16* __restrict__ W1, char* __restrict__ Wg2f,
                      int* __restrict__ ctrl){
  __shared__ float sh[64*65];
  int bx = blockIdx.x, tid = threadIdx.x;
  if (bx < 1024){
    int e = bx >> 6, dt = (bx >> 3) & 7, ot = bx & 7;
    const float* src = We + (size_t)e*262144 + (size_t)dt*64*512 + ot*64;
    #pragma unroll
    for (int it=0; it<16; ++it){ int idx = it*256+tid; int dl = idx>>6, ol = idx&63;
      sh[dl*65+ol] = src[dl*512+ol]; }
    __syncthreads();
    f16* dst = Wt + (size_t)e*262144 + (size_t)ot*64*512 + dt*64;
    #pragma unroll
    for (int it=0; it<16; ++it){ int idx = it*256+tid; int ol = idx>>6, dl = idx&63;
      dst[(size_t)ol*512+dl] = (f16)sh[dl*65+ol]; }
  } else if (bx < 1040){
    int q = bx - 1024;
    int dt = q >> 1, ht = q & 1;
    const float* src = Wg1 + (size_t)dt*64*128 + ht*64;
    #pragma unroll
    for (int it=0; it<16; ++it){ int idx = it*256+tid; int dl = idx>>6, ol = idx&63;
      sh[dl*65+ol] = src[dl*128+ol]; }
    __syncthreads();
    #pragma unroll
    for (int it=0; it<16; ++it){ int idx = it*256+tid; int ol = idx>>6, dl = idx&63;
      W1[(size_t)(ht*64+ol)*512 + dt*64+dl] = (f16)sh[dl*65+ol]; }
  } else {
    // Wg2 -> MFMA B-fragment order: frag[ks][lane][j] = Wg2[ks*32+(lane>>4)*8+j][lane&15]
    int ks = tid >> 6, l = tid & 63;
    int col = l & 15, kb = ks*32 + ((l >> 4) << 3);
    f16x8 v;
    #pragma unroll
    for (int j=0;j<8;++j) v[j] = (f16)Wg2[(kb+j)*16 + col];
    *(f16x8*)(Wg2f + (ks*64+l)*16) = v;
    #pragma unroll
    for (int i = 0; i < 8; ++i) ctrl[tid + i*256] = 0;   // zero CTRL (8KB)
  }
}

// ---- kgate: 128 tok/block fp16 gating + x-f16 producer + pair histogram.
// 256 thr = 4 waves (2Mx2N), wave tile 64 tok x 64 hid, BK=64, 8 K-steps.
__global__ __launch_bounds__(256) void kgate(
    const float* __restrict__ x, const f16* __restrict__ W1, const char* __restrict__ Wg2f,
    const float* __restrict__ bg1, const float* __restrict__ bg2,
    f16* __restrict__ xbf,
    int2* __restrict__ gate_e, float2* __restrict__ gate_g,
    int* __restrict__ refine_cnt, int* __restrict__ refine_list, int* __restrict__ counts)
{
  __shared__ __align__(16) char sm[76800];
  const int BOFF = 32768;   // B dbuf 2x16KB: [32K,48K),[48K,64K); A dbuf 2x16KB: [0,32K)
  const int LOGI = 67584;   // logits f32 [128][16]
  const int HIST = 75776;   // 256 ints
  int tid = threadIdx.x, bid = blockIdx.x;
  int lane = tid & 63, w = tid >> 6, wm = w >> 1, wn = w & 1;
  int l15 = lane & 15, l4 = lane >> 4;
  int t0 = bid * 128;
  int ar = tid >> 1, ach = tid & 1;
  const float* xrow = x + (size_t)(t0 + ar) * DDIM;
  char* xbfb = (char*)xbf;
  f32x4 acc[4][4];
  #pragma unroll
  for (int n=0;n<4;++n){
    float bb = bg1[wn*64 + n*16 + l15];
    f32x4 z = {bb, bb, bb, bb};
    #pragma unroll
    for (int m=0;m<4;++m) acc[m][n] = z;
  }
  // A stage: row ar (0..127), cols ach*32..+31 of the 64-col K-step
  auto stageA = [&](int ks, char* abuf){
    float fv[32];
    #pragma unroll
    for (int q=0;q<8;++q) *(float4*)&fv[q*4] = *(const float4*)(xrow + ks*64 + ach*32 + q*4);
    f16x8 h0 = pack8f(fv), h1 = pack8f(fv+8), h2 = pack8f(fv+16), h3 = pack8f(fv+24);
    *(f16x8*)(abuf + ar*128 + (((ach*4+0) ^ (ar & 7)) << 4)) = h0;
    *(f16x8*)(abuf + ar*128 + (((ach*4+1) ^ (ar & 7)) << 4)) = h1;
    *(f16x8*)(abuf + ar*128 + (((ach*4+2) ^ (ar & 7)) << 4)) = h2;
    *(f16x8*)(abuf + ar*128 + (((ach*4+3) ^ (ar & 7)) << 4)) = h3;
    if (xbf){
      char* xd = xbfb + (size_t)(t0+ar)*1024 + ks*128 + ach*64;
      *(f16x8*)xd = h0; *(f16x8*)(xd+16) = h1; *(f16x8*)(xd+32) = h2; *(f16x8*)(xd+48) = h3;
    }
  };
  // B stage [128 hid][64 k] 16KB via gload_lds, pre-swizzled source; W1 pitch 1024B
  auto stageB = [&](int ks, char* lds){
    const char* gb = (const char*)W1 + ks*128;
    #pragma unroll
    for (int i = 0; i < 4; ++i){
      int lin = i*4096 + tid*16;
      int r = lin >> 7, g = (lin >> 4) & 7;
      load_lds16(gb + r*1024 + ((g ^ (r & 7)) << 4), lds + i*4096 + ((tid >> 6) << 10));
    }
  };
  stageB(0, sm + BOFF); stageA(0, sm);
  for (int ks = 0; ks < 8; ++ks){
    int b = ks & 1;
    asm volatile("s_waitcnt vmcnt(0)" ::: "memory");
    __syncthreads();
    if (ks < 7) stageB(ks+1, sm + BOFF + (b^1)*16384);
    const char* Ab = sm + b*16384;
    const char* Bb = sm + BOFF + b*16384;
    f16x8 ah[4][2], bh[4][2];
    #pragma unroll
    for (int m=0;m<4;++m)
      #pragma unroll
      for (int kf=0;kf<2;++kf) ah[m][kf] = readF64h(Ab, wm*64 + m*16 + l15, kf*4 + l4);
    #pragma unroll
    for (int n=0;n<4;++n)
      #pragma unroll
      for (int kf=0;kf<2;++kf) bh[n][kf] = readF64h(Bb, wn*64 + n*16 + l15, kf*4 + l4);
    #pragma unroll
    for (int m=0;m<4;++m)
      #pragma unroll
      for (int n=0;n<4;++n){
        acc[m][n] = MFMAH(ah[m][0], bh[n][0], acc[m][n]);
        acc[m][n] = MFMAH(ah[m][1], bh[n][1], acc[m][n]);
      }
    if (ks < 7) stageA(ks+1, sm + (b^1)*16384);
  }
  __syncthreads();
  // prefetch Wg2 B-fragments (lane-indexed, same for all waves)
  uint4 wgf[4];
  #pragma unroll
  for (int ksq=0; ksq<4; ++ksq) wgf[ksq] = *(const uint4*)(Wg2f + (ksq*64+lane)*16);
  // GELU (exact erf) -> h f32 [128][132] at sm+0 (A/B bufs dead)
  float* hl = (float*)sm;
  #pragma unroll
  for (int m=0;m<4;++m)
    #pragma unroll
    for (int n=0;n<4;++n)
      #pragma unroll
      for (int j=0;j<4;++j){
        int row = wm*64 + m*16 + (l4 << 2) + j;
        int col = wn*64 + n*16 + l15;
        float uv = acc[m][n][j];
        hl[row*132 + col] = 0.5f * uv * (1.0f + erff(uv * 0.70710678118654752f));
      }
  __syncthreads();
  // GEMM2 via MFMA: logits[128][16]; wave w -> token rows w*32..+31 (2 sub-MFMAs)
  {
    float bb2 = bg2[l15];
    float* ll = (float*)(sm + LOGI);
    #pragma unroll
    for (int sub=0; sub<2; ++sub){
      f32x4 acc2 = {bb2, bb2, bb2, bb2};
      #pragma unroll
      for (int ksq=0; ksq<4; ++ksq){
        const float* hp = (const float*)sm + (w*32 + sub*16 + l15)*132 + ksq*32 + l4*8;
        f16x8 afr;
        #pragma unroll
        for (int j=0;j<8;++j) afr[j] = (f16)hp[j];
        acc2 = MFMAH(afr, *(const f16x8*)&wgf[ksq], acc2);
      }
      #pragma unroll
      for (int j=0;j<4;++j) ll[(w*32 + sub*16 + l4*4 + j)*16 + l15] = acc2[j];
    }
  }
  int* hist = (int*)(sm + HIST);
  hist[tid] = 0;
  __syncthreads();
  if (tid < 128){
    int t = t0 + tid;
    const float* l = (const float*)(sm + LOGI) + tid*16;
    float b1 = -1e30f, b2 = -1e30f, b3 = -1e30f; int e1 = 0, e2 = 0;
    #pragma unroll
    for (int e = 0; e < 16; ++e){
      float v = l[e];
      if (v > b1){ b3 = b2; b2 = b1; e2 = e1; b1 = v; e1 = e; }
      else if (v > b2){ b3 = b2; b2 = v; e2 = e; }
      else if (v > b3){ b3 = v; }
    }
    float s = 0.f;
    #pragma unroll
    for (int e = 0; e < 16; ++e) s += expf(l[e] - b1);
    float inv = 1.f / s;
    gate_e[t] = make_int2(e1, e2);
    gate_g[t] = make_float2(inv + 1e-4f, expf(b2 - b1) * inv + 1e-4f);
    if (b2 - b3 < 1e-3f){            // fp16-path margin: flag ambiguous top2/top3
      int pos = atomicAdd(refine_cnt, 1);
      refine_list[pos] = t;
    }
    int pa = min(e1, e2), pb = max(e1, e2);
    atomicAdd(&hist[pa*16 + pb], 1);
  }
  __syncthreads();
  if (hist[tid]) atomicAdd(&counts[tid], hist[tid]);
}

// ---- krefine: exact fp64 gating for flagged tokens (4-way chains); patches counts.
__global__ __launch_bounds__(128) void krefine(
    const float* __restrict__ x, const float* __restrict__ Wg1, const float* __restrict__ bg1,
    const float* __restrict__ Wg2, const float* __restrict__ bg2,
    const int* __restrict__ refine_cnt, const int* __restrict__ refine_list,
    int2* __restrict__ gate_e, float2* __restrict__ gate_g, int* __restrict__ counts)
{
  __shared__ float  xs[512];
  __shared__ double hd[128];
  __shared__ double ld[16];
  int tid = threadIdx.x;
  int rc = *refine_cnt;
  for (int i = blockIdx.x; i < rc; i += gridDim.x){
    __syncthreads();
    int t = refine_list[i];
    *(float4*)(xs + tid*4) = *(const float4*)(x + (size_t)t*DDIM + tid*4);
    __syncthreads();
    double a0=0.0, a1=0.0, a2=0.0, a3=0.0;
    for (int d = 0; d < 512; d += 4){
      a0 += (double)xs[d]   * (double)Wg1[(d)*128 + tid];
      a1 += (double)xs[d+1] * (double)Wg1[(d+1)*128 + tid];
      a2 += (double)xs[d+2] * (double)Wg1[(d+2)*128 + tid];
      a3 += (double)xs[d+3] * (double)Wg1[(d+3)*128 + tid];
    }
    double a = (double)bg1[tid] + ((a0+a1)+(a2+a3));
    hd[tid] = 0.5 * a * (1.0 + erf(a * 0.70710678118654752440));
    __syncthreads();
    if (tid < 16){
      double s0=0.0, s1=0.0;
      for (int k = 0; k < 128; k += 2){
        s0 += hd[k]   * (double)Wg2[(k)*16 + tid];
        s1 += hd[k+1] * (double)Wg2[(k+1)*16 + tid];
      }
      ld[tid] = (double)bg2[tid] + s0 + s1;
    }
    __syncthreads();
    if (tid == 0){
      int2 olde = gate_e[t];
      double b1 = -1e300, b2 = -1e300; int e1 = 0, e2 = 0;
      for (int e = 0; e < 16; ++e){
        double v = ld[e];
        if (v > b1){ b2 = b1; e2 = e1; b1 = v; e1 = e; }
        else if (v > b2){ b2 = v; e2 = e; }
      }
      double s = 0.0;
      for (int e = 0; e < 16; ++e) s += exp(ld[e] - b1);
      double inv = 1.0 / s;
      int oldp = min(olde.x, olde.y)*16 + max(olde.x, olde.y);
      int newp = min(e1, e2)*16 + max(e1, e2);
      if (oldp != newp){ atomicSub(&counts[oldp], 1); atomicAdd(&counts[newp], 1); }
      gate_e[t] = make_int2(e1, e2);
      gate_g[t] = make_float2((float)(inv + 1e-4), (float)(exp(b2 - b1) * inv + 1e-4));
    }
  }
}

// ---- kscatter: fused scan + scatter. Each block computes the 256-pair prefix scan
// locally (wave 0); block 0 additionally writes global bases + tile list + ntiles.
__global__ __launch_bounds__(256) void kscatter(
    const int2* __restrict__ gate_e, const float2* __restrict__ gate_g,
    const int* __restrict__ counts,
    int* __restrict__ bases, int* __restrict__ cursors,
    int* __restrict__ tile_pair, int* __restrict__ tile_row0, int* __restrict__ ntiles,
    int* __restrict__ pair_tok, float2* __restrict__ pair_g, int ts)
{
  __shared__ int h[256];
  __shared__ int gb[256];
  __shared__ int bl[257];
  int tid = threadIdx.x;
  h[tid] = 0;
  if (tid < 64){
    int l = tid;
    int4 c = *(const int4*)(counts + l*4);
    int s = c.x + c.y + c.z + c.w;
    int ps = s;
    #pragma unroll
    for (int d = 1; d < 64; d <<= 1){ int v = __shfl_up(ps, d); if (l >= d) ps += v; }
    int ex = ps - s;
    bl[4*l+0] = ex;
    bl[4*l+1] = ex + c.x;
    bl[4*l+2] = ex + c.x + c.y;
    bl[4*l+3] = ex + c.x + c.y + c.z;
    if (l == 63) bl[256] = ex + s;
    if (blockIdx.x == 0){
      *(int4*)(bases + 4*l) = make_int4(bl[4*l], bl[4*l+1], bl[4*l+2], bl[4*l+3]);
      if (l == 63) bases[256] = ex + s;
      int t0 = (c.x + ts-1)/ts, t1 = (c.y + ts-1)/ts, t2 = (c.z + ts-1)/ts, t3 = (c.w + ts-1)/ts;
      int tsum = t0 + t1 + t2 + t3;
      int pt = tsum;
      #pragma unroll
      for (int d = 1; d < 64; d <<= 1){ int v = __shfl_up(pt, d); if (l >= d) pt += v; }
      int ext = pt - tsum;
      if (l == 63) *ntiles = ext + tsum;
      int tb = ext;
      int cc[4] = {c.x, c.y, c.z, c.w};
      #pragma unroll
      for (int j = 0; j < 4; ++j){
        int pp = 4*l + j;
        for (int r = 0; r < cc[j]; r += ts){ tile_pair[tb] = pp; tile_row0[tb] = r; ++tb; }
      }
    }
  }
  __syncthreads();
  int t = blockIdx.x*256 + tid;
  int2 ee = gate_e[t]; float2 gg = gate_g[t];
  int a, b; float ga, gbv;
  if (ee.x < ee.y){ a = ee.x; b = ee.y; ga = gg.x; gbv = gg.y; }
  else            { a = ee.y; b = ee.x; ga = gg.y; gbv = gg.x; }
  int p = a*16 + b;
  int off = atomicAdd(&h[p], 1);
  __syncthreads();
  if (h[tid]) gb[tid] = bl[tid] + atomicAdd(&cursors[tid], h[tid]);
  __syncthreads();
  int slot = gb[p] + off;
  pair_tok[slot] = t;
  pair_g[slot] = make_float2(ga, gbv);
}

// ======== kexpert2: 256x256 pair-bucket GEMM, 8-phase counted-vmcnt schedule ====
#define SB0 __builtin_amdgcn_sched_barrier(0)
#define PH_MID do{ __builtin_amdgcn_s_barrier(); \
                   asm volatile("s_waitcnt lgkmcnt(0)"); SB0; }while(0)
#define PH_END do{ SB0; __builtin_amdgcn_s_barrier(); }while(0)

#define RDA(hp, mb) do{ \
  _Pragma("unroll") for (int m_=0;m_<4;++m_){ \
    int r_ = ((mb)+m_)*16 + l15; \
    af[m_][0] = readF64h(hp, r_, l4); \
    af[m_][1] = readF64h(hp, r_, 4+l4); }}while(0)
#define RDB(hp, bv, nb) do{ \
  _Pragma("unroll") for (int n_=0;n_<2;++n_){ \
    int r_ = bln + ((nb)+n_)*16 + l15; \
    bv[n_][0] = readF64h(hp, r_, l4); \
    bv[n_][1] = readF64h(hp, r_, 4+l4); }}while(0)
#define MMAC(bv, mb, nb) do{ \
  __builtin_amdgcn_s_setprio(1); \
  _Pragma("unroll") for (int m_=0;m_<4;++m_){ \
    _Pragma("unroll") for (int n_=0;n_<2;++n_){ \
      acc[(mb)+m_][(nb)+n_] = MFMAH(af[m_][0], bv[n_][0], acc[(mb)+m_][(nb)+n_]); \
      acc[(mb)+m_][(nb)+n_] = MFMAH(af[m_][1], bv[n_][1], acc[(mb)+m_][(nb)+n_]); }} \
  __builtin_amdgcn_s_setprio(0); \
}while(0)

__global__ __launch_bounds__(512, 2) void kexpert2(
    const f16* __restrict__ xbf, const f16* __restrict__ Wt, const float* __restrict__ be,
    float* __restrict__ out,
    const int* __restrict__ counts, const int* __restrict__ bases,
    const int* __restrict__ tile_pair, const int* __restrict__ tile_row0, const int* __restrict__ ntiles,
    const int* __restrict__ pair_tok, const float2* __restrict__ pair_g)
{
  __shared__ __align__(16) char sm[134144];
  const int BBASE = 65536, LTOK = 131072, LG = 132096;
  int bid = blockIdx.x;
  int tile = ((bid >> 4) << 3) | (bid & 7);   // col-block pair shares XCD
  int nt = (bid >> 3) & 1;
  if (tile >= *ntiles) return;
  int p = tile_pair[tile], row0 = tile_row0[tile];
  int base = bases[p], cnt = counts[p];
  int eA = p >> 4, eB = p & 15;
  int tid = threadIdx.x, lane = tid & 63, w = tid >> 6;
  int wm = w >> 2, wn = w & 3;
  int l15 = lane & 15, l4 = lane >> 4;
  int bln = (wn & 1) * 64;
  if (tid < 256){
    int rr = row0 + tid; bool v = rr < cnt;
    ((int*)(sm + LTOK))[tid] = v ? pair_tok[base + rr] : -1;
    ((float2*)(sm + LG))[tid] = v ? pair_g[base + rr] : make_float2(0.f, 1.f);
  }
  __syncthreads();

  int rr0 = tid >> 3;
  int sw = ((tid & 7) ^ (rr0 & 7)) << 4;
  const char* xb = (const char*)xbf;
  const char* srcA[2][2];
  #pragma unroll
  for (int h = 0; h < 2; ++h)
    #pragma unroll
    for (int i = 0; i < 2; ++i){
      int tk = ((const int*)(sm + LTOK))[h*128 + i*64 + rr0];
      if (tk < 0) tk = 0;
      srcA[h][i] = xb + (size_t)tk*1024 + sw;
    }
  const char* srcB0 = (const char*)Wt + (size_t)eA*524288 + (size_t)(nt*256 + rr0)*1024 + sw;
  long long edelt = ((long long)eB - eA) * 524288;
  char* dA = sm + w*1024;
  char* dB = sm + BBASE + w*1024;

  auto stA = [&](int t, int h){
    if (t >= NT) return;
    int ks = t & 7, bf_ = t & 1;
    load_lds16(srcA[h][0] + ks*128, dA + bf_*32768 + h*16384);
    load_lds16(srcA[h][1] + ks*128, dA + bf_*32768 + h*16384 + 8192);
  };
  auto stB = [&](int t, int h){
    if (t >= NT) return;
    int ks = t & 7, bf_ = t & 1;
    long long eo = ((t >= 8) ? edelt : 0) + ks*128;
    load_lds16(srcB0 + h*131072 + eo,         dB + bf_*32768 + h*16384);
    load_lds16(srcB0 + h*131072 + 65536 + eo, dB + bf_*32768 + h*16384 + 8192);
  };

  const char* A0 = sm + wm*16384;
  const char* A1 = A0 + 32768;
  const char* B0 = sm + BBASE + (wn >> 1)*16384;
  const char* B1 = B0 + 32768;

  f32x4 acc[8][4];
  #pragma unroll
  for (int m = 0; m < 8; ++m)
    #pragma unroll
    for (int n = 0; n < 4; ++n) acc[m][n] = (f32x4){0.f,0.f,0.f,0.f};

  stA(0,0); stA(0,1); stB(0,0); stB(0,1); stB(1,0); stB(1,1);
  asm volatile("s_waitcnt vmcnt(4)"); SB0;
  __builtin_amdgcn_s_barrier();

  f16x8 af[4][2], bL[2][2], bH[2][2];
  #pragma unroll 1
  for (int i = 0; i < 8; ++i){
    int t0 = 2*i, t1 = t0 + 1;
    RDA(A0, 0); RDB(B0, bL, 0); stA(t1, 0);
    PH_MID; MMAC(bL, 0, 0); PH_END;
    RDB(B0, bH, 2); stA(t1, 1);
    PH_MID; MMAC(bH, 0, 2); PH_END;
    RDA(A0, 4); stB(t0+2, 0);
    PH_MID; MMAC(bH, 4, 2); PH_END;
    stB(t0+2, 1);
    if (i != 7) { asm volatile("s_waitcnt vmcnt(4)"); SB0; }
    else        { asm volatile("s_waitcnt vmcnt(0)"); SB0; }
    PH_MID; MMAC(bL, 4, 0); PH_END;
    RDA(A1, 0); RDB(B1, bL, 0); stA(t0+2, 0);
    PH_MID; MMAC(bL, 0, 0); PH_END;
    RDB(B1, bH, 2); stA(t0+2, 1);
    PH_MID; MMAC(bH, 0, 2); PH_END;
    RDA(A1, 4); stB(t1+2, 0);
    PH_MID; MMAC(bH, 4, 2); PH_END;
    stB(t1+2, 1);
    if (i != 7) { asm volatile("s_waitcnt vmcnt(4)"); SB0; }
    PH_MID; MMAC(bL, 4, 0); PH_END;
    if (i == 3){            // expert switch: fold gate-A into accumulator
      #pragma unroll
      for (int m = 0; m < 8; ++m)
        #pragma unroll
        for (int j = 0; j < 4; ++j){
          int row = wm*128 + m*16 + l4*4 + j;
          float2 g2 = ((const float2*)(sm + LG))[row];
          float r_ = g2.x / g2.y;
          #pragma unroll
          for (int n = 0; n < 4; ++n) acc[m][n][j] *= r_;
        }
    }
  }

  float bcA[4], bcB[4];
  #pragma unroll
  for (int n = 0; n < 4; ++n){
    int col = nt*256 + wn*64 + n*16 + l15;
    bcA[n] = be[(size_t)eA*DDIM + col];
    bcB[n] = be[(size_t)eB*DDIM + col];
  }
  #pragma unroll
  for (int m = 0; m < 8; ++m)
    #pragma unroll
    for (int j = 0; j < 4; ++j){
      int row = wm*128 + m*16 + l4*4 + j;
      int tk = ((const int*)(sm + LTOK))[row];
      if (tk >= 0){
        float2 g2 = ((const float2*)(sm + LG))[row];
        float* orow = out + (size_t)tk*DDIM + nt*256 + wn*64;
        #pragma unroll
        for (int n = 0; n < 4; ++n)
          orow[n*16 + l15] = g2.y*acc[m][n][j] + g2.x*bcA[n] + g2.y*bcB[n];
      }
    }
}

// ---- kexpertF: fallback (no x-f16 room): 128x128 pair-bucket GEMM, reg-staged A.
__global__ __launch_bounds__(256, 2) void kexpertF(
    const float* __restrict__ x,
    const f16* __restrict__ Wt, const float* __restrict__ be,
    float* __restrict__ out,
    const int* __restrict__ counts, const int* __restrict__ bases,
    const int* __restrict__ tile_pair, const int* __restrict__ tile_row0, const int* __restrict__ ntiles,
    const int* __restrict__ pair_tok, const float2* __restrict__ pair_g)
{
  __shared__ __align__(16) char sm[67072];
  const int ABUF = 0, BBUF = 32768, LTOK = 65536, LGOFF = 66048;
  int tile = blockIdx.x >> 2, nt = blockIdx.x & 3;
  if (tile >= *ntiles) return;
  int p = tile_pair[tile], row0 = tile_row0[tile];
  int base = bases[p], cnt = counts[p];
  int eA = p >> 4, eB = p & 15;
  int tid = threadIdx.x, lane = tid & 63;
  int w = tid >> 6, wm = w >> 1, wn = w & 1;
  if (tid < 128){
    int rr = row0 + tid; bool v = rr < cnt;
    ((int*)(sm + LTOK))[tid] = v ? pair_tok[base + rr] : -1;
    ((float2*)(sm + LGOFF))[tid] = v ? pair_g[base + rr] : make_float2(0.f, 0.f);
  }
  __syncthreads();
  const char* wb = (const char*)Wt;
  int grp = tid >> 3, gch = tid & 7;
  int swz = (gch ^ (grp & 7)) << 4;
  long long edelt = ((long long)eB - (long long)eA) * 524288;
  const char* srcB[4];
  #pragma unroll
  for (int i = 0; i < 4; ++i)
    srcB[i] = wb + (long long)eA*524288 + (size_t)(nt*128 + i*32 + grp)*1024 + swz;
  int arow = tid >> 1, ach = tid & 1;
  int tkr = ((const int*)(sm + LTOK))[arow];
  if (tkr < 0) tkr = 0;
  const float* xrow = x + (size_t)tkr*DDIM + ach*32;
  int ldst = (w << 10);
  #pragma unroll
  for (int i = 0; i < 4; ++i) load_lds16(srcB[i], sm + BBUF + i*4096 + ldst);
  {
    #pragma unroll
    for (int q2 = 0; q2 < 4; ++q2){
      float fv[8];
      *(float4*)&fv[0] = *(const float4*)(xrow + q2*8);
      *(float4*)&fv[4] = *(const float4*)(xrow + q2*8 + 4);
      f16x8 hv = pack8f(fv);
      int g = ach*4 + q2;
      *(f16x8*)(sm + ABUF + arow*128 + ((g ^ (arow & 7)) << 4)) = hv;
    }
  }
  f32x4 acc[4][4], res[4][4];
  #pragma unroll
  for (int m=0;m<4;++m)
    #pragma unroll
    for (int n=0;n<4;++n) acc[m][n] = (f32x4){0.f,0.f,0.f,0.f};
  for (int u = 0; u < 16; ++u){
    int b = u & 1;
    asm volatile("s_waitcnt vmcnt(0)" ::: "memory");
    __syncthreads();
    int un = u + 1;
    f16x8 hv[4];
    if (un < 16){
      int b2 = un & 1;
      long long aoff = (long long)(un & 7) * 128;
      long long boff = aoff + ((un >> 3) ? edelt : 0);
      #pragma unroll
      for (int i = 0; i < 4; ++i)
        load_lds16(srcB[i] + boff, sm + BBUF + b2*16384 + i*4096 + ldst);
      const float* xr = xrow + (un & 7)*64;
      #pragma unroll
      for (int q2 = 0; q2 < 4; ++q2){
        float fv[8];
        *(float4*)&fv[0] = *(const float4*)(xr + q2*8);
        *(float4*)&fv[4] = *(const float4*)(xr + q2*8 + 4);
        hv[q2] = pack8f(fv);
      }
    }
    const char* Ab = sm + ABUF + b*16384;
    const char* Bb = sm + BBUF + b*16384;
    f16x8 af2[4][2], bf2[4][2];
    #pragma unroll
    for (int m=0;m<4;++m){
      int r = wm*64 + m*16 + (lane & 15);
      af2[m][0] = readF64h(Ab, r, (lane >> 4));
      af2[m][1] = readF64h(Ab, r, 4 + (lane >> 4));
    }
    #pragma unroll
    for (int n=0;n<4;++n){
      int r = wn*64 + n*16 + (lane & 15);
      bf2[n][0] = readF64h(Bb, r, (lane >> 4));
      bf2[n][1] = readF64h(Bb, r, 4 + (lane >> 4));
    }
    #pragma unroll
    for (int m=0;m<4;++m)
      #pragma unroll
      for (int n=0;n<4;++n){
        acc[m][n] = MFMAH(af2[m][0], bf2[n][0], acc[m][n]);
        acc[m][n] = MFMAH(af2[m][1], bf2[n][1], acc[m][n]);
      }
    if (un < 16){
      int b2 = un & 1;
      #pragma unroll
      for (int q2 = 0; q2 < 4; ++q2){
        int g = ach*4 + q2;
        *(f16x8*)(sm + ABUF + b2*16384 + arow*128 + ((g ^ (arow & 7)) << 4)) = hv[q2];
      }
    }
    if (u == 7){
      const float* bev = be + (size_t)eA*DDIM + nt*128;
      float bcol[4];
      #pragma unroll
      for (int n=0;n<4;++n) bcol[n] = bev[wn*64 + n*16 + (lane & 15)];
      #pragma unroll
      for (int m=0;m<4;++m)
        #pragma unroll
        for (int j=0;j<4;++j){
          int row = wm*64 + m*16 + ((lane >> 4) << 2) + j;
          float g = ((const float2*)(sm + LGOFF))[row].x;
          #pragma unroll
          for (int n=0;n<4;++n){
            res[m][n][j] = g * (acc[m][n][j] + bcol[n]);
            acc[m][n][j] = 0.f;
          }
        }
    }
    if (u == 15){
      const float* bev = be + (size_t)eB*DDIM + nt*128;
      float bcol[4];
      #pragma unroll
      for (int n=0;n<4;++n) bcol[n] = bev[wn*64 + n*16 + (lane & 15)];
      #pragma unroll
      for (int m=0;m<4;++m)
        #pragma unroll
        for (int j=0;j<4;++j){
          int row = wm*64 + m*16 + ((lane >> 4) << 2) + j;
          int tk = ((const int*)(sm + LTOK))[row];
          float g = ((const float2*)(sm + LGOFF))[row].y;
          if (tk >= 0){
            float* orow = out + (size_t)tk*DDIM + nt*128;
            #pragma unroll
            for (int n=0;n<4;++n)
              orow[wn*64 + n*16 + (lane & 15)] = res[m][n][j] + g * (acc[m][n][j] + bcol[n]);
          }
        }
    }
  }
}

// ---- host launch --------------------------------------------------------------
extern "C" void kernel_launch(void* const* d_in, const int* in_sizes, int n_in,
                              void* d_out, int out_size, void* d_ws, size_t ws_size,
                              hipStream_t stream)
{
  const float* x   = (const float*)d_in[0];
  const float* Wg1 = (const float*)d_in[1];
  const float* bg1 = (const float*)d_in[2];
  const float* Wg2 = (const float*)d_in[3];
  const float* bg2 = (const float*)d_in[4];
  const float* We  = (const float*)d_in[5];
  const float* be  = (const float*)d_in[6];
  float* out = (float*)d_out;
  char* ws = (char*)d_ws;

  f16*  Wt          = (f16*)(ws + 0);             // 8,388,608
  f16*  W1          = (f16*)(ws + 8388608);       //   131,072
  char* Wg2f        = ws + 8519680;               //     4,096 (of 131,072 slot)
  char* CTRL        = ws + 8650752;               //     8,192
  int*  refine_cnt  = (int*)(CTRL);
  int*  ntiles      = (int*)(CTRL + 4);
  int*  counts      = (int*)(CTRL + 64);          // 256 ints
  int*  cursors     = (int*)(CTRL + 2048);        // 256 ints
  int*  bases       = (int*)(CTRL + 4096);        // 257 ints
  int2*   gate_e    = (int2*)(ws + 8658944);      // 1,048,576
  float2* gate_g    = (float2*)(ws + 9707520);    // 1,048,576
  int*  refine_list = (int*)(ws + 10756096);      //   524,288
  int*  pair_tok    = (int*)(ws + 11280384);      //   524,288
  float2* pair_g    = (float2*)(ws + 11804672);   // 1,048,576
  int*  tile_pair   = (int*)(ws + 12853248);      //    10,240
  int*  tile_row0   = (int*)(ws + 12863488);      //    10,240
  const size_t XBF_OFF = 16777216ull;
  const size_t XBF_BYTES = (size_t)NTOK * DDIM * 2;   // 134 MB (f16 x)
  bool bf16a = ws_size >= XBF_OFF + XBF_BYTES;
  f16* xbf = bf16a ? (f16*)(ws + XBF_OFF) : nullptr;

  hipLaunchKernelGGL(kconv,    dim3(1041), dim3(256), 0, stream, We, Wg1, Wg2, Wt, W1, Wg2f,
                     (int*)CTRL);
  hipLaunchKernelGGL(kgate,    dim3(1024), dim3(256), 0, stream, x, W1, Wg2f, bg1, bg2,
                     xbf, gate_e, gate_g, refine_cnt, refine_list, counts);
  hipLaunchKernelGGL(krefine,  dim3(512),  dim3(128), 0, stream, x, Wg1, bg1, Wg2, bg2,
                     refine_cnt, refine_list, gate_e, gate_g, counts);
  hipLaunchKernelGGL(kscatter, dim3(512),  dim3(256), 0, stream, gate_e, gate_g, counts,
                     bases, cursors, tile_pair, tile_row0, ntiles, pair_tok, pair_g,
                     bf16a ? 256 : 128);
  if (bf16a)
    hipLaunchKernelGGL(kexpert2, dim3(1408), dim3(512), 0, stream, xbf, Wt, be, out,
                       counts, bases, tile_pair, tile_row0, ntiles, pair_tok, pair_g);
  else
    hipLaunchKernelGGL(kexpertF, dim3(5120), dim3(256), 0, stream, x, Wt, be, out,
                       counts, bases, tile_pair, tile_row0, ntiles, pair_tok, pair_g);
  (void)in_sizes; (void)n_in; (void)out_size; (void)ws_size;
}